// Round 4
// baseline (3754.048 us; speedup 1.0000x reference)
//
#include <hip/hip_runtime.h>

typedef unsigned short u16;
typedef unsigned int   u32;
typedef __attribute__((ext_vector_type(8))) unsigned short u16x8;
typedef __attribute__((ext_vector_type(4))) unsigned short u16x4;
typedef __attribute__((ext_vector_type(8))) short bf16x8;
typedef __attribute__((ext_vector_type(4))) float f32x4;

__device__ __forceinline__ float b2f(u16 u) { return __uint_as_float(((u32)u) << 16); }
__device__ __forceinline__ u16 f2b(float f) {
  u32 u = __float_as_uint(f);
  return (u16)((u + 0x7FFFu + ((u >> 16) & 1u)) >> 16);   // RNE
}

// ---------------- weight prep: transpose to (N x K) row-major + cvt bf16 ----
// wt layout (elements):
//   [0..786432)        : WqT[3]   (3 x 512x512), WqT[i] at i*262144
//   [786432..2359296)  : (WkT,WvT)[3] pairs: kv_i at 786432+i*524288 (K rows 0..511, V rows 512..1023)
//   [2359296..2883584) : f0T (1024x512)
//   [2883584..3407872) : f1T (1024x512)
__global__ __launch_bounds__(256) void prep_w(const float* __restrict__ Wq,
    const float* __restrict__ Wk, const float* __restrict__ Wv,
    const float* __restrict__ f0, const float* __restrict__ f1,
    u16* __restrict__ wt) {
  int t = blockIdx.x * 256 + threadIdx.x;
  float v;
  if (t < 786432) {
    int i = t >> 18, r = t & 262143, n = r >> 9, k = r & 511;
    v = Wq[(size_t)(i << 18) + k * 512 + n];
  } else if (t < 2359296) {
    int r = t - 786432, i = r >> 19, r2 = r & 524287;
    int n = (r2 >> 9) & 511, k = r2 & 511;
    v = ((r2 >> 18) ? Wv : Wk)[(size_t)(i << 18) + k * 512 + n];
  } else if (t < 2883584) {
    int r = t - 2359296, n = r >> 9, k = r & 511;
    v = f0[(size_t)k * 1024 + n];
  } else {
    int r = t - 2883584, n = r >> 9, k = r & 511;
    v = f1[(size_t)k * 1024 + n];
  }
  wt[t] = f2b(v);
}

// ---------------- LayerNorm (fp32 in) -> xn bf16, xb bf16(raw) --------------
__global__ __launch_bounds__(256) void ln_f32(const float* __restrict__ x,
    const float* __restrict__ g, const float* __restrict__ bta,
    u16* __restrict__ xn, u16* __restrict__ xb) {
  int row = (blockIdx.x << 2) + (threadIdx.x >> 6);
  int lane = threadIdx.x & 63;
  const float* xr = x + (size_t)row * 512 + (lane << 3);
  float4 a = *(const float4*)xr;
  float4 c = *(const float4*)(xr + 4);
  float v[8] = {a.x, a.y, a.z, a.w, c.x, c.y, c.z, c.w};
  float s = 0.f, s2 = 0.f;
#pragma unroll
  for (int j = 0; j < 8; ++j) { s += v[j]; s2 += v[j] * v[j]; }
  for (int off = 32; off; off >>= 1) { s += __shfl_xor(s, off); s2 += __shfl_xor(s2, off); }
  float mean = s * (1.f / 512.f);
  float var = s2 * (1.f / 512.f) - mean * mean;
  float rs = rsqrtf(var + 1e-5f);
  const float* gp = g + (lane << 3);
  const float* bp = bta + (lane << 3);
  u16x8 pb, pn;
#pragma unroll
  for (int j = 0; j < 8; ++j) {
    pb[j] = f2b(v[j]);
    pn[j] = f2b((v[j] - mean) * rs * gp[j] + bp[j]);
  }
  *(u16x8*)(xb + (size_t)row * 512 + (lane << 3)) = pb;
  *(u16x8*)(xn + (size_t)row * 512 + (lane << 3)) = pn;
}

// ---------------- LayerNorm (bf16 in) -> bf16 out ---------------------------
__global__ __launch_bounds__(256) void ln_b16(const u16* __restrict__ xin,
    const float* __restrict__ g, const float* __restrict__ bta,
    u16* __restrict__ xout) {
  int row = (blockIdx.x << 2) + (threadIdx.x >> 6);
  int lane = threadIdx.x & 63;
  u16x8 u = *(const u16x8*)(xin + (size_t)row * 512 + (lane << 3));
  float v[8];
#pragma unroll
  for (int j = 0; j < 8; ++j) v[j] = b2f(u[j]);
  float s = 0.f, s2 = 0.f;
#pragma unroll
  for (int j = 0; j < 8; ++j) { s += v[j]; s2 += v[j] * v[j]; }
  for (int off = 32; off; off >>= 1) { s += __shfl_xor(s, off); s2 += __shfl_xor(s2, off); }
  float mean = s * (1.f / 512.f);
  float var = s2 * (1.f / 512.f) - mean * mean;
  float rs = rsqrtf(var + 1e-5f);
  const float* gp = g + (lane << 3);
  const float* bp = bta + (lane << 3);
  u16x8 pn;
#pragma unroll
  for (int j = 0; j < 8; ++j) pn[j] = f2b((v[j] - mean) * rs * gp[j] + bp[j]);
  *(u16x8*)(xout + (size_t)row * 512 + (lane << 3)) = pn;
}

// ---------------- GEMM: C(MxN bf16) = A(Mx512 bf16) * Bt(Nx512 bf16)^T ------
// m97-style 128x128 tile, BK=64, 4 waves, global_load_lds 16B staging.
template <bool GELU>
__global__ __launch_bounds__(256, 2) void gemm_bt(const u16* __restrict__ A,
    const u16* __restrict__ Bt, u16* __restrict__ C,
    const float* __restrict__ bias, int M, int N) {
  __shared__ __align__(16) u16 As[128 * 64];
  __shared__ __align__(16) u16 Bs[128 * 64];
  int tid = threadIdx.x;
  int w = tid >> 6, lane = tid & 63;
  int m0 = blockIdx.y << 7, n0 = blockIdx.x << 7;
  int wm = (w & 1) << 6, wn = (w >> 1) << 6;
  f32x4 acc[4][4] = {};
  const int r_off = lane >> 3;        // 0..7 (row within 8-row chunk)
  const int k_off = (lane & 7) << 3;  // 0..56 (bf16 col)
  for (int kt = 0; kt < 8; ++kt) {
    __syncthreads();
#pragma unroll
    for (int j = 0; j < 4; ++j) {
      int q = (w << 2) + j;  // chunk 0..15, 8 rows each
      const u16* gA = A + (size_t)(m0 + (q << 3) + r_off) * 512 + (kt << 6) + k_off;
      __builtin_amdgcn_global_load_lds(
          (const __attribute__((address_space(1))) u32*)gA,
          (__attribute__((address_space(3))) u32*)(As + (q << 9)), 16, 0, 0);
      const u16* gB = Bt + (size_t)(n0 + (q << 3) + r_off) * 512 + (kt << 6) + k_off;
      __builtin_amdgcn_global_load_lds(
          (const __attribute__((address_space(1))) u32*)gB,
          (__attribute__((address_space(3))) u32*)(Bs + (q << 9)), 16, 0, 0);
    }
    asm volatile("s_waitcnt vmcnt(0)" ::: "memory");
    __syncthreads();
#pragma unroll
    for (int kk = 0; kk < 2; ++kk) {
      int ko = (kk << 5) + ((lane >> 4) << 3);
      bf16x8 af[4], bfr[4];
#pragma unroll
      for (int mi = 0; mi < 4; ++mi)
        af[mi] = *(const bf16x8*)(As + (wm + (mi << 4) + (lane & 15)) * 64 + ko);
#pragma unroll
      for (int ni = 0; ni < 4; ++ni)
        bfr[ni] = *(const bf16x8*)(Bs + (wn + (ni << 4) + (lane & 15)) * 64 + ko);
#pragma unroll
      for (int mi = 0; mi < 4; ++mi)
#pragma unroll
        for (int ni = 0; ni < 4; ++ni)
          acc[mi][ni] = __builtin_amdgcn_mfma_f32_16x16x32_bf16(af[mi], bfr[ni], acc[mi][ni], 0, 0, 0);
    }
  }
  int cr = (lane >> 4) << 2, cc = lane & 15;
#pragma unroll
  for (int mi = 0; mi < 4; ++mi) {
#pragma unroll
    for (int ni = 0; ni < 4; ++ni) {
      int col = n0 + wn + (ni << 4) + cc;
      float bv = 0.f;
      if (GELU) bv = bias[col];
#pragma unroll
      for (int j = 0; j < 4; ++j) {
        int row = m0 + wm + (mi << 4) + cr + j;
        float v = acc[mi][ni][j];
        if (GELU) { v += bv; v = 0.5f * v * (1.f + erff(v * 0.70710678118f)); }
        C[(size_t)row * N + col] = f2b(v);
      }
    }
  }
}

// ---------------- attention: per-batch block ---------------------------------
// Q: (nb*25, 512) bf16; KV: (nb*NKV, 1024) bf16 [K cols 0..511, V 512..1023]
// 512 threads: h = tid>>6 (8 heads), n = (tid&63)>>1 (row, <25), half = tid&1.
// Compute phase: each lane owns 32 head dims; shfl_xor(1) completes dots.
// Epilogue: o*sc staged to LDS (fp32, XOR-swizzled), then 512 threads stream
// out row-major with lane-contiguous float4 (full-line HBM bursts, no RMW).
template <int NKV, bool INIT>
__global__ __launch_bounds__(512, 4) void attn(const u16* __restrict__ Q,
    const u16* __restrict__ KV, const u16* __restrict__ xb, float* __restrict__ out) {
  constexpr int PH1 = NKV * 2048 + 25600;           // KV bytes + Q bytes
  constexpr int LDSB = PH1 > 51200 ? PH1 : 51200;   // >= 25*512*4 fp32 o-stage
  __shared__ __align__(16) char smem[LDSB];
  u16* KVl = (u16*)smem;
  u16* Ql  = (u16*)(smem + NKV * 2048);
  float* Ost = (float*)smem;                        // overlays KVl(+Ql), phase 2
  int b = blockIdx.x, tid = threadIdx.x;
  const u16* kvb = KV + (size_t)b * (NKV * 1024);
  for (int e = tid * 8; e < NKV * 1024; e += 4096)
    *(u16x8*)(KVl + e) = *(const u16x8*)(kvb + e);
  const u16* qg = Q + (size_t)b * 12800;
  for (int e = tid * 8; e < 12800; e += 4096) {
    int se = e ^ (((e >> 9) & 7) << 3);             // row-XOR swizzle (16B slots)
    *(u16x8*)(Ql + se) = *(const u16x8*)(qg + e);
  }
  __syncthreads();
  int h = tid >> 6, r = tid & 63, n = r >> 1, half = r & 1;
  int dbase = (h << 6) + (half << 5);
  float o[32];
  float sc = 0.f;
  if (n < 25) {
    int qsw = (n & 7) << 3;
    float q[32];
#pragma unroll
    for (int i = 0; i < 4; ++i) {
      u16x8 u = *(const u16x8*)(Ql + ((n * 512 + dbase + (i << 3)) ^ qsw));
#pragma unroll
      for (int j = 0; j < 8; ++j) q[i * 8 + j] = b2f(u[j]);
    }
    float s[NKV];
    float mx = -1e30f;
#pragma unroll
    for (int m = 0; m < NKV; ++m) {
      const u16* kr = KVl + m * 1024 + dbase;       // same addr across lanes: broadcast
      float p = 0.f;
#pragma unroll
      for (int i = 0; i < 4; ++i) {
        u16x8 u = *(const u16x8*)(kr + (i << 3));
#pragma unroll
        for (int j = 0; j < 8; ++j) p += q[i * 8 + j] * b2f(u[j]);
      }
      float d = p + __shfl_xor(p, 1);
      s[m] = d * 0.125f;
      mx = fmaxf(mx, s[m]);
    }
    float sum = 0.f;
#pragma unroll
    for (int m = 0; m < NKV; ++m) { s[m] = __expf(s[m] - mx); sum += s[m]; }
#pragma unroll
    for (int k = 0; k < 32; ++k) o[k] = 0.f;
#pragma unroll
    for (int m = 0; m < NKV; ++m) {
      float a = s[m];
      const u16* vr = KVl + m * 1024 + 512 + dbase;
#pragma unroll
      for (int i = 0; i < 4; ++i) {
        u16x8 u = *(const u16x8*)(vr + (i << 3));
#pragma unroll
        for (int j = 0; j < 8; ++j) o[i * 8 + j] += a * b2f(u[j]);
      }
    }
    sc = (1.f / sum) * (1.f / 3.f);
  }
  __syncthreads();                                  // all reads of KVl/Ql done
  if (n < 25) {
    int base = n * 512 + dbase, osw = (n & 7) << 2; // XOR on float4 slots
#pragma unroll
    for (int j = 0; j < 8; ++j) {
      f32x4 v;
      v[0] = o[j * 4 + 0] * sc; v[1] = o[j * 4 + 1] * sc;
      v[2] = o[j * 4 + 2] * sc; v[3] = o[j * 4 + 3] * sc;
      *(f32x4*)(Ost + ((base + (j << 2)) ^ osw)) = v;
    }
  }
  __syncthreads();
  size_t bb = (size_t)b * 12800;
  for (int e = tid * 4; e < 12800; e += 2048) {
    int fe = e ^ (((e >> 9) & 7) << 2);
    f32x4 sv = *(const f32x4*)(Ost + fe);
    f32x4 rr;
    if (INIT) {
      u16x4 xv = *(const u16x4*)(xb + bb + e);
      rr[0] = sv[0] + b2f(xv[0]); rr[1] = sv[1] + b2f(xv[1]);
      rr[2] = sv[2] + b2f(xv[2]); rr[3] = sv[3] + b2f(xv[3]);
    } else {
      f32x4 pv = *(const f32x4*)(out + bb + e);
      rr = sv + pv;
    }
    *(f32x4*)(out + bb + e) = rr;
  }
}

// ---------------- pool: fc2 + softmax + S^T * l_feat ------------------------
// h: (nb*NIN, 1024) bf16 (gelu'd fc1 out); lf: (nb*NIN, 512) bf16 raw l_feat
// w2: (1024, NOUT) fp32; out lout: (nb*NOUT, 512) bf16
template <int NIN, int NOUT>
__global__ __launch_bounds__(256) void pool(const u16* __restrict__ h,
    const u16* __restrict__ lf, const float* __restrict__ w2,
    const float* __restrict__ b2, u16* __restrict__ lout) {
  __shared__ __align__(16) float W2l[1024 * NOUT];
  __shared__ __align__(16) u16 Xl[NIN * 512];
  __shared__ __align__(16) float Sl[NIN * NOUT];
  int b = blockIdx.x, tid = threadIdx.x;
  for (int e = tid; e < 1024 * NOUT; e += 256) W2l[e] = w2[e];
  for (int e = tid * 8; e < NIN * 512; e += 2048)
    *(u16x8*)(Xl + e) = *(const u16x8*)(lf + (size_t)b * NIN * 512 + e);
  __syncthreads();
  if (tid < NIN * 8) {
    int nn = tid >> 3, sub = tid & 7;
    float p[NOUT] = {};
    const u16* hr = h + (size_t)(b * NIN + nn) * 1024;
    for (int cc = 0; cc < 128; ++cc) {
      int c = sub + (cc << 3);
      float hv = b2f(hr[c]);
#pragma unroll
      for (int s2 = 0; s2 < NOUT; ++s2) p[s2] += hv * W2l[c * NOUT + s2];
    }
#pragma unroll
    for (int s2 = 0; s2 < NOUT; ++s2) {
      p[s2] += __shfl_down(p[s2], 4, 8);
      p[s2] += __shfl_down(p[s2], 2, 8);
      p[s2] += __shfl_down(p[s2], 1, 8);
    }
    if (sub == 0) {
      float mx = -1e30f;
#pragma unroll
      for (int s2 = 0; s2 < NOUT; ++s2) { p[s2] += b2[s2]; mx = fmaxf(mx, p[s2]); }
      float sum = 0.f;
#pragma unroll
      for (int s2 = 0; s2 < NOUT; ++s2) { p[s2] = __expf(p[s2] - mx); sum += p[s2]; }
      float inv = 1.f / sum;
#pragma unroll
      for (int s2 = 0; s2 < NOUT; ++s2) Sl[nn * NOUT + s2] = p[s2] * inv;
    }
  }
  __syncthreads();
  int c0 = tid << 1;
#pragma unroll
  for (int s2 = 0; s2 < NOUT; ++s2) {
    float a0 = 0.f, a1 = 0.f;
#pragma unroll
    for (int nn = 0; nn < NIN; ++nn) {
      float wv = Sl[nn * NOUT + s2];
      a0 += wv * b2f(Xl[nn * 512 + c0]);
      a1 += wv * b2f(Xl[nn * 512 + c0 + 1]);
    }
    u32 pk = (u32)f2b(a0) | ((u32)f2b(a1) << 16);
    *(u32*)(lout + (size_t)(b * NOUT + s2) * 512 + c0) = pk;
  }
}

// ---------------- launcher ---------------------------------------------------
extern "C" void kernel_launch(void* const* d_in, const int* in_sizes, int n_in,
                              void* d_out, int out_size, void* d_ws, size_t ws_size,
                              hipStream_t stream) {
  const float* src = (const float*)d_in[0];
  // d_in[1] spatial_relation: unused (dead in reference output math)
  const float* g    = (const float*)d_in[2];
  const float* bt   = (const float*)d_in[3];
  const float* Wq   = (const float*)d_in[4];
  const float* Wk   = (const float*)d_in[5];
  const float* Wv   = (const float*)d_in[6];
  const float* f0w  = (const float*)d_in[7];
  const float* f0b  = (const float*)d_in[8];
  const float* f0w2 = (const float*)d_in[9];
  const float* f0b2 = (const float*)d_in[10];
  const float* f1w  = (const float*)d_in[11];
  const float* f1b  = (const float*)d_in[12];
  const float* f1w2 = (const float*)d_in[13];
  const float* f1b2 = (const float*)d_in[14];
  float* out = (float*)d_out;
  char* ws = (char*)d_ws;

  // workspace layout (bytes), peak ~503 MB (validated round 2)
  u16* wt  = (u16*)(ws + 0);
  u16* xn  = (u16*)(ws + 6815744);
  u16* xb  = (u16*)(ws + 111673344);
  u16* qb  = (u16*)(ws + 216530944);
  u16* B1  = (u16*)(ws + 321388544);
  u16* l1  = (u16*)(ws + 426246144);
  u16* kn1 = (u16*)(ws + 476577792);
  u16* l2  = qb;                       // 28 MB, alive pool1->ln only
  u16* kn2 = qb + 14680064;            // alive ln->KV2 gemm only

  prep_w<<<13312, 256, 0, stream>>>(Wq, Wk, Wv, f0w, f1w, wt);
  ln_f32<<<25600, 256, 0, stream>>>(src, g, bt, xn, xb);

  // scale 0: Q gemm full, KV gemm + attn in 2 half-slices sharing B1 (100 MB)
  gemm_bt<false><<<dim3(4, 800), 256, 0, stream>>>(xn, wt, qb, nullptr, 102400, 512);
  for (int s = 0; s < 2; ++s) {
    size_t ro = (size_t)s * 51200;   // row offset (2048 batches)
    gemm_bt<false><<<dim3(8, 400), 256, 0, stream>>>(xn + ro * 512, wt + 786432, B1, nullptr, 51200, 1024);
    attn<25, true><<<2048, 512, 0, stream>>>(qb + ro * 512, B1, xb + ro * 512, out + ro * 512);
  }

  // pool 0: fc1(gelu) gemm + pool in 2 half-slices, h half lives in B1
  for (int s = 0; s < 2; ++s) {
    size_t ro = (size_t)s * 51200;
    gemm_bt<true><<<dim3(8, 400), 256, 0, stream>>>(xb + ro * 512, wt + 2359296, B1, f0b, 51200, 1024);
    pool<25, 12><<<2048, 256, 0, stream>>>(B1, xb + ro * 512, f0w2, f0b2, l1 + (size_t)s * 2048 * 12 * 512);
  }
  ln_b16<<<12288, 256, 0, stream>>>(l1, g, bt, kn1);

  // scale 1
  gemm_bt<false><<<dim3(4, 800), 256, 0, stream>>>(xn, wt + 262144, qb, nullptr, 102400, 512);
  gemm_bt<false><<<dim3(8, 384), 256, 0, stream>>>(kn1, wt + 786432 + 524288, B1, nullptr, 49152, 1024);
  attn<12, false><<<4096, 512, 0, stream>>>(qb, B1, nullptr, out);

  // pool 1: h1 (96 MB) in B1 after attn1
  gemm_bt<true><<<dim3(8, 384), 256, 0, stream>>>(l1, wt + 2883584, B1, f1b, 49152, 1024);
  pool<12, 7><<<4096, 256, 0, stream>>>(B1, l1, f1w2, f1b2, l2);
  ln_b16<<<7168, 256, 0, stream>>>(l2, g, bt, kn2);

  // scale 2: KV gemm BEFORE Q gemm (kn2 lives in qb region; Q2 gemm clobbers it)
  gemm_bt<false><<<dim3(8, 224), 256, 0, stream>>>(kn2, wt + 786432 + 1048576, B1, nullptr, 28672, 1024);
  gemm_bt<false><<<dim3(4, 800), 256, 0, stream>>>(xn, wt + 524288, qb, nullptr, 102400, 512);
  attn<7, false><<<4096, 512, 0, stream>>>(qb, B1, nullptr, out);
}

// Round 5
// 1836.384 us; speedup vs baseline: 2.0443x; 2.0443x over previous
//
#include <hip/hip_runtime.h>

typedef unsigned short u16;
typedef unsigned int   u32;
typedef __attribute__((ext_vector_type(8))) unsigned short u16x8;
typedef __attribute__((ext_vector_type(4))) unsigned short u16x4;
typedef __attribute__((ext_vector_type(8))) short bf16x8;
typedef __attribute__((ext_vector_type(4))) float f32x4;

__device__ __forceinline__ float b2f(u16 u) { return __uint_as_float(((u32)u) << 16); }
__device__ __forceinline__ u16 f2b(float f) {
  u32 u = __float_as_uint(f);
  return (u16)((u + 0x7FFFu + ((u >> 16) & 1u)) >> 16);   // RNE
}

// ---------------- weight prep: transpose to (N x K) row-major + cvt bf16 ----
// wt layout (elements):
//   [0..786432)        : WqT[3]   (3 x 512x512), WqT[i] at i*262144
//   [786432..2359296)  : (WkT,WvT)[3] pairs: kv_i at 786432+i*524288 (K rows 0..511, V rows 512..1023)
//   [2359296..2883584) : f0T (1024x512)
//   [2883584..3407872) : f1T (1024x512)
__global__ __launch_bounds__(256) void prep_w(const float* __restrict__ Wq,
    const float* __restrict__ Wk, const float* __restrict__ Wv,
    const float* __restrict__ f0, const float* __restrict__ f1,
    u16* __restrict__ wt) {
  int t = blockIdx.x * 256 + threadIdx.x;
  float v;
  if (t < 786432) {
    int i = t >> 18, r = t & 262143, n = r >> 9, k = r & 511;
    v = Wq[(size_t)(i << 18) + k * 512 + n];
  } else if (t < 2359296) {
    int r = t - 786432, i = r >> 19, r2 = r & 524287;
    int n = (r2 >> 9) & 511, k = r2 & 511;
    v = ((r2 >> 18) ? Wv : Wk)[(size_t)(i << 18) + k * 512 + n];
  } else if (t < 2883584) {
    int r = t - 2359296, n = r >> 9, k = r & 511;
    v = f0[(size_t)k * 1024 + n];
  } else {
    int r = t - 2883584, n = r >> 9, k = r & 511;
    v = f1[(size_t)k * 1024 + n];
  }
  wt[t] = f2b(v);
}

// ---------------- LayerNorm (fp32 in) -> xn bf16, xb bf16(raw) --------------
__global__ __launch_bounds__(256) void ln_f32(const float* __restrict__ x,
    const float* __restrict__ g, const float* __restrict__ bta,
    u16* __restrict__ xn, u16* __restrict__ xb) {
  int row = (blockIdx.x << 2) + (threadIdx.x >> 6);
  int lane = threadIdx.x & 63;
  const float* xr = x + (size_t)row * 512 + (lane << 3);
  float4 a = *(const float4*)xr;
  float4 c = *(const float4*)(xr + 4);
  float v[8] = {a.x, a.y, a.z, a.w, c.x, c.y, c.z, c.w};
  float s = 0.f, s2 = 0.f;
#pragma unroll
  for (int j = 0; j < 8; ++j) { s += v[j]; s2 += v[j] * v[j]; }
  for (int off = 32; off; off >>= 1) { s += __shfl_xor(s, off); s2 += __shfl_xor(s2, off); }
  float mean = s * (1.f / 512.f);
  float var = s2 * (1.f / 512.f) - mean * mean;
  float rs = rsqrtf(var + 1e-5f);
  const float* gp = g + (lane << 3);
  const float* bp = bta + (lane << 3);
  u16x8 pb, pn;
#pragma unroll
  for (int j = 0; j < 8; ++j) {
    pb[j] = f2b(v[j]);
    pn[j] = f2b((v[j] - mean) * rs * gp[j] + bp[j]);
  }
  *(u16x8*)(xb + (size_t)row * 512 + (lane << 3)) = pb;
  *(u16x8*)(xn + (size_t)row * 512 + (lane << 3)) = pn;
}

// ---------------- LayerNorm (bf16 in) -> bf16 out ---------------------------
__global__ __launch_bounds__(256) void ln_b16(const u16* __restrict__ xin,
    const float* __restrict__ g, const float* __restrict__ bta,
    u16* __restrict__ xout) {
  int row = (blockIdx.x << 2) + (threadIdx.x >> 6);
  int lane = threadIdx.x & 63;
  u16x8 u = *(const u16x8*)(xin + (size_t)row * 512 + (lane << 3));
  float v[8];
#pragma unroll
  for (int j = 0; j < 8; ++j) v[j] = b2f(u[j]);
  float s = 0.f, s2 = 0.f;
#pragma unroll
  for (int j = 0; j < 8; ++j) { s += v[j]; s2 += v[j] * v[j]; }
  for (int off = 32; off; off >>= 1) { s += __shfl_xor(s, off); s2 += __shfl_xor(s2, off); }
  float mean = s * (1.f / 512.f);
  float var = s2 * (1.f / 512.f) - mean * mean;
  float rs = rsqrtf(var + 1e-5f);
  const float* gp = g + (lane << 3);
  const float* bp = bta + (lane << 3);
  u16x8 pn;
#pragma unroll
  for (int j = 0; j < 8; ++j) pn[j] = f2b((v[j] - mean) * rs * gp[j] + bp[j]);
  *(u16x8*)(xout + (size_t)row * 512 + (lane << 3)) = pn;
}

// ---------------- GEMM: C(MxN bf16) = A(Mx512 bf16) * Bt(Nx512 bf16)^T ------
// m97-style 128x128 tile, BK=64, 4 waves, global_load_lds 16B staging.
template <bool GELU>
__global__ __launch_bounds__(256, 2) void gemm_bt(const u16* __restrict__ A,
    const u16* __restrict__ Bt, u16* __restrict__ C,
    const float* __restrict__ bias, int M, int N) {
  __shared__ __align__(16) u16 As[128 * 64];
  __shared__ __align__(16) u16 Bs[128 * 64];
  int tid = threadIdx.x;
  int w = tid >> 6, lane = tid & 63;
  int m0 = blockIdx.y << 7, n0 = blockIdx.x << 7;
  int wm = (w & 1) << 6, wn = (w >> 1) << 6;
  f32x4 acc[4][4] = {};
  const int r_off = lane >> 3;        // 0..7 (row within 8-row chunk)
  const int k_off = (lane & 7) << 3;  // 0..56 (bf16 col)
  for (int kt = 0; kt < 8; ++kt) {
    __syncthreads();
#pragma unroll
    for (int j = 0; j < 4; ++j) {
      int q = (w << 2) + j;  // chunk 0..15, 8 rows each
      const u16* gA = A + (size_t)(m0 + (q << 3) + r_off) * 512 + (kt << 6) + k_off;
      __builtin_amdgcn_global_load_lds(
          (const __attribute__((address_space(1))) u32*)gA,
          (__attribute__((address_space(3))) u32*)(As + (q << 9)), 16, 0, 0);
      const u16* gB = Bt + (size_t)(n0 + (q << 3) + r_off) * 512 + (kt << 6) + k_off;
      __builtin_amdgcn_global_load_lds(
          (const __attribute__((address_space(1))) u32*)gB,
          (__attribute__((address_space(3))) u32*)(Bs + (q << 9)), 16, 0, 0);
    }
    asm volatile("s_waitcnt vmcnt(0)" ::: "memory");
    __syncthreads();
#pragma unroll
    for (int kk = 0; kk < 2; ++kk) {
      int ko = (kk << 5) + ((lane >> 4) << 3);
      bf16x8 af[4], bfr[4];
#pragma unroll
      for (int mi = 0; mi < 4; ++mi)
        af[mi] = *(const bf16x8*)(As + (wm + (mi << 4) + (lane & 15)) * 64 + ko);
#pragma unroll
      for (int ni = 0; ni < 4; ++ni)
        bfr[ni] = *(const bf16x8*)(Bs + (wn + (ni << 4) + (lane & 15)) * 64 + ko);
#pragma unroll
      for (int mi = 0; mi < 4; ++mi)
#pragma unroll
        for (int ni = 0; ni < 4; ++ni)
          acc[mi][ni] = __builtin_amdgcn_mfma_f32_16x16x32_bf16(af[mi], bfr[ni], acc[mi][ni], 0, 0, 0);
    }
  }
  int cr = (lane >> 4) << 2, cc = lane & 15;
#pragma unroll
  for (int mi = 0; mi < 4; ++mi) {
#pragma unroll
    for (int ni = 0; ni < 4; ++ni) {
      int col = n0 + wn + (ni << 4) + cc;
      float bv = 0.f;
      if (GELU) bv = bias[col];
#pragma unroll
      for (int j = 0; j < 4; ++j) {
        int row = m0 + wm + (mi << 4) + cr + j;
        float v = acc[mi][ni][j];
        if (GELU) { v += bv; v = 0.5f * v * (1.f + erff(v * 0.70710678118f)); }
        C[(size_t)row * N + col] = f2b(v);
      }
    }
  }
}

// ---------------- attention: per-batch block ---------------------------------
// Q: (nb*25, 512) bf16; KV: (nb*NKV, 1024) bf16 [K cols 0..511, V 512..1023]
// 512 threads: h = tid>>6 (8 heads), n = (tid&63)>>1 (row, <25), half = tid&1
// (each lane owns 32 of the 64 head dims; shfl_xor(1) completes dots).
// __launch_bounds__(512, 2): 2 blocks/CU -> 128-VGPR budget; per-thread live
// state (~100 regs) fits WITHOUT scratch spills (the round-3/4 killer: (512,4)
// capped VGPRs at 64 and spilled ~50 floats/thread to scratch -> GBs of HBM).
template <int NKV, bool INIT>
__global__ __launch_bounds__(512, 2) void attn(const u16* __restrict__ Q,
    const u16* __restrict__ KV, const u16* __restrict__ xb, float* __restrict__ out) {
  __shared__ __align__(16) u16 KVl[NKV * 1024];
  int b = blockIdx.x, tid = threadIdx.x;
  const u16* kvb = KV + (size_t)b * (NKV * 1024);
  for (int e = tid * 8; e < NKV * 1024; e += 4096)
    *(u16x8*)(KVl + e) = *(const u16x8*)(kvb + e);
  __syncthreads();
  int h = tid >> 6, r = tid & 63, n = r >> 1, half = r & 1;
  if (n < 25) {
    int dbase = (h << 6) + (half << 5);
    const u16* qr = Q + (size_t)(b * 25 + n) * 512 + dbase;
    float q[32];
#pragma unroll
    for (int i = 0; i < 4; ++i) {
      u16x8 u = *(const u16x8*)(qr + (i << 3));
#pragma unroll
      for (int j = 0; j < 8; ++j) q[i * 8 + j] = b2f(u[j]);
    }
    float s[NKV];
    float mx = -1e30f;
#pragma unroll
    for (int m = 0; m < NKV; ++m) {
      const u16* kr = KVl + m * 1024 + dbase;   // 2 addrs/wave: broadcast, no conflict
      float p = 0.f;
#pragma unroll
      for (int i = 0; i < 4; ++i) {
        u16x8 u = *(const u16x8*)(kr + (i << 3));
#pragma unroll
        for (int j = 0; j < 8; ++j) p += q[i * 8 + j] * b2f(u[j]);
      }
      float d = p + __shfl_xor(p, 1);
      s[m] = d * 0.125f;
      mx = fmaxf(mx, s[m]);
    }
    float sum = 0.f;
#pragma unroll
    for (int m = 0; m < NKV; ++m) { s[m] = __expf(s[m] - mx); sum += s[m]; }
    float o[32] = {};
#pragma unroll
    for (int m = 0; m < NKV; ++m) {
      float a = s[m];
      const u16* vr = KVl + m * 1024 + 512 + dbase;
#pragma unroll
      for (int i = 0; i < 4; ++i) {
        u16x8 u = *(const u16x8*)(vr + (i << 3));
#pragma unroll
        for (int j = 0; j < 8; ++j) o[i * 8 + j] += a * b2f(u[j]);
      }
    }
    float sc = (1.f / sum) * (1.f / 3.f);
    // epilogue: lane-pair (n, half=0/1) covers 256 B contiguous -> full-line HBM
    float* orow = out + (size_t)(b * 25 + n) * 512 + dbase;
    if (INIT) {
      const u16* xrow = xb + (size_t)(b * 25 + n) * 512 + dbase;
#pragma unroll
      for (int i = 0; i < 4; ++i) {
        u16x8 xv = *(const u16x8*)(xrow + (i << 3));
#pragma unroll
        for (int j = 0; j < 8; j += 4) {
          float4 rr;
          rr.x = o[i * 8 + j + 0] * sc + b2f(xv[j + 0]);
          rr.y = o[i * 8 + j + 1] * sc + b2f(xv[j + 1]);
          rr.z = o[i * 8 + j + 2] * sc + b2f(xv[j + 2]);
          rr.w = o[i * 8 + j + 3] * sc + b2f(xv[j + 3]);
          *(float4*)(orow + i * 8 + j) = rr;
        }
      }
    } else {
#pragma unroll
      for (int i = 0; i < 8; ++i) {
        float4 pv = *(const float4*)(orow + i * 4);
        float4 rr;
        rr.x = o[i * 4 + 0] * sc + pv.x;
        rr.y = o[i * 4 + 1] * sc + pv.y;
        rr.z = o[i * 4 + 2] * sc + pv.z;
        rr.w = o[i * 4 + 3] * sc + pv.w;
        *(float4*)(orow + i * 4) = rr;
      }
    }
  }
}

// ---------------- pool: fc2 + softmax + S^T * l_feat ------------------------
// h: (nb*NIN, 1024) bf16 (gelu'd fc1 out); lf: (nb*NIN, 512) bf16 raw l_feat
// w2: (1024, NOUT) fp32; out lout: (nb*NOUT, 512) bf16
template <int NIN, int NOUT>
__global__ __launch_bounds__(256) void pool(const u16* __restrict__ h,
    const u16* __restrict__ lf, const float* __restrict__ w2,
    const float* __restrict__ b2, u16* __restrict__ lout) {
  __shared__ __align__(16) float W2l[1024 * NOUT];
  __shared__ __align__(16) u16 Xl[NIN * 512];
  __shared__ __align__(16) float Sl[NIN * NOUT];
  int b = blockIdx.x, tid = threadIdx.x;
  for (int e = tid; e < 1024 * NOUT; e += 256) W2l[e] = w2[e];
  for (int e = tid * 8; e < NIN * 512; e += 2048)
    *(u16x8*)(Xl + e) = *(const u16x8*)(lf + (size_t)b * NIN * 512 + e);
  __syncthreads();
  if (tid < NIN * 8) {
    int nn = tid >> 3, sub = tid & 7;
    float p[NOUT] = {};
    const u16* hr = h + (size_t)(b * NIN + nn) * 1024;
    for (int cc = 0; cc < 128; ++cc) {
      int c = sub + (cc << 3);
      float hv = b2f(hr[c]);
#pragma unroll
      for (int s2 = 0; s2 < NOUT; ++s2) p[s2] += hv * W2l[c * NOUT + s2];
    }
#pragma unroll
    for (int s2 = 0; s2 < NOUT; ++s2) {
      p[s2] += __shfl_down(p[s2], 4, 8);
      p[s2] += __shfl_down(p[s2], 2, 8);
      p[s2] += __shfl_down(p[s2], 1, 8);
    }
    if (sub == 0) {
      float mx = -1e30f;
#pragma unroll
      for (int s2 = 0; s2 < NOUT; ++s2) { p[s2] += b2[s2]; mx = fmaxf(mx, p[s2]); }
      float sum = 0.f;
#pragma unroll
      for (int s2 = 0; s2 < NOUT; ++s2) { p[s2] = __expf(p[s2] - mx); sum += p[s2]; }
      float inv = 1.f / sum;
#pragma unroll
      for (int s2 = 0; s2 < NOUT; ++s2) Sl[nn * NOUT + s2] = p[s2] * inv;
    }
  }
  __syncthreads();
  int c0 = tid << 1;
#pragma unroll
  for (int s2 = 0; s2 < NOUT; ++s2) {
    float a0 = 0.f, a1 = 0.f;
#pragma unroll
    for (int nn = 0; nn < NIN; ++nn) {
      float wv = Sl[nn * NOUT + s2];
      a0 += wv * b2f(Xl[nn * 512 + c0]);
      a1 += wv * b2f(Xl[nn * 512 + c0 + 1]);
    }
    u32 pk = (u32)f2b(a0) | ((u32)f2b(a1) << 16);
    *(u32*)(lout + (size_t)(b * NOUT + s2) * 512 + c0) = pk;
  }
}

// ---------------- launcher ---------------------------------------------------
extern "C" void kernel_launch(void* const* d_in, const int* in_sizes, int n_in,
                              void* d_out, int out_size, void* d_ws, size_t ws_size,
                              hipStream_t stream) {
  const float* src = (const float*)d_in[0];
  // d_in[1] spatial_relation: unused (dead in reference output math)
  const float* g    = (const float*)d_in[2];
  const float* bt   = (const float*)d_in[3];
  const float* Wq   = (const float*)d_in[4];
  const float* Wk   = (const float*)d_in[5];
  const float* Wv   = (const float*)d_in[6];
  const float* f0w  = (const float*)d_in[7];
  const float* f0b  = (const float*)d_in[8];
  const float* f0w2 = (const float*)d_in[9];
  const float* f0b2 = (const float*)d_in[10];
  const float* f1w  = (const float*)d_in[11];
  const float* f1b  = (const float*)d_in[12];
  const float* f1w2 = (const float*)d_in[13];
  const float* f1b2 = (const float*)d_in[14];
  float* out = (float*)d_out;
  char* ws = (char*)d_ws;

  // workspace layout (bytes), peak ~503 MB (validated round 2)
  u16* wt  = (u16*)(ws + 0);
  u16* xn  = (u16*)(ws + 6815744);
  u16* xb  = (u16*)(ws + 111673344);
  u16* qb  = (u16*)(ws + 216530944);
  u16* B1  = (u16*)(ws + 321388544);
  u16* l1  = (u16*)(ws + 426246144);
  u16* kn1 = (u16*)(ws + 476577792);
  u16* l2  = qb;                       // 28 MB, alive pool1->ln only
  u16* kn2 = qb + 14680064;            // alive ln->KV2 gemm only

  prep_w<<<13312, 256, 0, stream>>>(Wq, Wk, Wv, f0w, f1w, wt);
  ln_f32<<<25600, 256, 0, stream>>>(src, g, bt, xn, xb);

  // scale 0: Q gemm full, KV gemm + attn in 2 half-slices sharing B1 (100 MB)
  gemm_bt<false><<<dim3(4, 800), 256, 0, stream>>>(xn, wt, qb, nullptr, 102400, 512);
  for (int s = 0; s < 2; ++s) {
    size_t ro = (size_t)s * 51200;   // row offset (2048 batches)
    gemm_bt<false><<<dim3(8, 400), 256, 0, stream>>>(xn + ro * 512, wt + 786432, B1, nullptr, 51200, 1024);
    attn<25, true><<<2048, 512, 0, stream>>>(qb + ro * 512, B1, xb + ro * 512, out + ro * 512);
  }

  // pool 0: fc1(gelu) gemm + pool in 2 half-slices, h half lives in B1
  for (int s = 0; s < 2; ++s) {
    size_t ro = (size_t)s * 51200;
    gemm_bt<true><<<dim3(8, 400), 256, 0, stream>>>(xb + ro * 512, wt + 2359296, B1, f0b, 51200, 1024);
    pool<25, 12><<<2048, 256, 0, stream>>>(B1, xb + ro * 512, f0w2, f0b2, l1 + (size_t)s * 2048 * 12 * 512);
  }
  ln_b16<<<12288, 256, 0, stream>>>(l1, g, bt, kn1);

  // scale 1
  gemm_bt<false><<<dim3(4, 800), 256, 0, stream>>>(xn, wt + 262144, qb, nullptr, 102400, 512);
  gemm_bt<false><<<dim3(8, 384), 256, 0, stream>>>(kn1, wt + 786432 + 524288, B1, nullptr, 49152, 1024);
  attn<12, false><<<4096, 512, 0, stream>>>(qb, B1, nullptr, out);

  // pool 1: h1 (96 MB) in B1 after attn1
  gemm_bt<true><<<dim3(8, 384), 256, 0, stream>>>(l1, wt + 2883584, B1, f1b, 49152, 1024);
  pool<12, 7><<<4096, 256, 0, stream>>>(B1, l1, f1w2, f1b2, l2);
  ln_b16<<<7168, 256, 0, stream>>>(l2, g, bt, kn2);

  // scale 2: KV gemm BEFORE Q gemm (kn2 lives in qb region; Q2 gemm clobbers it)
  gemm_bt<false><<<dim3(8, 224), 256, 0, stream>>>(kn2, wt + 786432 + 1048576, B1, nullptr, 28672, 1024);
  gemm_bt<false><<<dim3(4, 800), 256, 0, stream>>>(xn, wt + 524288, qb, nullptr, 102400, 512);
  attn<7, false><<<4096, 512, 0, stream>>>(qb, B1, nullptr, out);
}

// Round 6
// 1809.912 us; speedup vs baseline: 2.0742x; 1.0146x over previous
//
#include <hip/hip_runtime.h>

typedef unsigned short u16;
typedef unsigned int   u32;
typedef _Float16 f16;
typedef __attribute__((ext_vector_type(8))) unsigned short u16x8;
typedef __attribute__((ext_vector_type(8))) _Float16 f16x8;
typedef __attribute__((ext_vector_type(4))) float f32x4;

__device__ __forceinline__ u16 f2h(float f) {
  f16 h = (f16)f;
  return __builtin_bit_cast(u16, h);
}
__device__ __forceinline__ float h2f(u16 u) {
  return (float)__builtin_bit_cast(f16, u);
}

// ---------------- weight prep: transpose to (N x K) row-major + cvt f16 -----
// wt layout (elements):
//   [0..786432)        : WqT[3]   (3 x 512x512), WqT[i] at i*262144
//   [786432..2359296)  : (WkT,WvT)[3] pairs: kv_i at 786432+i*524288 (K rows 0..511, V rows 512..1023)
//   [2359296..2883584) : f0T (1024x512)
//   [2883584..3407872) : f1T (1024x512)
__global__ __launch_bounds__(256) void prep_w(const float* __restrict__ Wq,
    const float* __restrict__ Wk, const float* __restrict__ Wv,
    const float* __restrict__ f0, const float* __restrict__ f1,
    u16* __restrict__ wt) {
  int t = blockIdx.x * 256 + threadIdx.x;
  float v;
  if (t < 786432) {
    int i = t >> 18, r = t & 262143, n = r >> 9, k = r & 511;
    v = Wq[(size_t)(i << 18) + k * 512 + n];
  } else if (t < 2359296) {
    int r = t - 786432, i = r >> 19, r2 = r & 524287;
    int n = (r2 >> 9) & 511, k = r2 & 511;
    v = ((r2 >> 18) ? Wv : Wk)[(size_t)(i << 18) + k * 512 + n];
  } else if (t < 2883584) {
    int r = t - 2359296, n = r >> 9, k = r & 511;
    v = f0[(size_t)k * 1024 + n];
  } else {
    int r = t - 2883584, n = r >> 9, k = r & 511;
    v = f1[(size_t)k * 1024 + n];
  }
  wt[t] = f2h(v);
}

// ---------------- LayerNorm (fp32 in) -> xn f16, xb f16(raw) ----------------
__global__ __launch_bounds__(256) void ln_f32(const float* __restrict__ x,
    const float* __restrict__ g, const float* __restrict__ bta,
    u16* __restrict__ xn, u16* __restrict__ xb) {
  int row = (blockIdx.x << 2) + (threadIdx.x >> 6);
  int lane = threadIdx.x & 63;
  const float* xr = x + (size_t)row * 512 + (lane << 3);
  float4 a = *(const float4*)xr;
  float4 c = *(const float4*)(xr + 4);
  float v[8] = {a.x, a.y, a.z, a.w, c.x, c.y, c.z, c.w};
  float s = 0.f, s2 = 0.f;
#pragma unroll
  for (int j = 0; j < 8; ++j) { s += v[j]; s2 += v[j] * v[j]; }
  for (int off = 32; off; off >>= 1) { s += __shfl_xor(s, off); s2 += __shfl_xor(s2, off); }
  float mean = s * (1.f / 512.f);
  float var = s2 * (1.f / 512.f) - mean * mean;
  float rs = rsqrtf(var + 1e-5f);
  const float* gp = g + (lane << 3);
  const float* bp = bta + (lane << 3);
  u16x8 pb, pn;
#pragma unroll
  for (int j = 0; j < 8; ++j) {
    pb[j] = f2h(v[j]);
    pn[j] = f2h((v[j] - mean) * rs * gp[j] + bp[j]);
  }
  *(u16x8*)(xb + (size_t)row * 512 + (lane << 3)) = pb;
  *(u16x8*)(xn + (size_t)row * 512 + (lane << 3)) = pn;
}

// ---------------- LayerNorm (f16 in) -> f16 out -----------------------------
__global__ __launch_bounds__(256) void ln_b16(const u16* __restrict__ xin,
    const float* __restrict__ g, const float* __restrict__ bta,
    u16* __restrict__ xout) {
  int row = (blockIdx.x << 2) + (threadIdx.x >> 6);
  int lane = threadIdx.x & 63;
  f16x8 u = *(const f16x8*)(xin + (size_t)row * 512 + (lane << 3));
  float v[8];
#pragma unroll
  for (int j = 0; j < 8; ++j) v[j] = (float)u[j];
  float s = 0.f, s2 = 0.f;
#pragma unroll
  for (int j = 0; j < 8; ++j) { s += v[j]; s2 += v[j] * v[j]; }
  for (int off = 32; off; off >>= 1) { s += __shfl_xor(s, off); s2 += __shfl_xor(s2, off); }
  float mean = s * (1.f / 512.f);
  float var = s2 * (1.f / 512.f) - mean * mean;
  float rs = rsqrtf(var + 1e-5f);
  const float* gp = g + (lane << 3);
  const float* bp = bta + (lane << 3);
  u16x8 pn;
#pragma unroll
  for (int j = 0; j < 8; ++j) pn[j] = f2h((v[j] - mean) * rs * gp[j] + bp[j]);
  *(u16x8*)(xout + (size_t)row * 512 + (lane << 3)) = pn;
}

// ---------------- GEMM: C(MxN f16) = A(Mx512 f16) * Bt(Nx512 f16)^T ---------
// m97-style 128x128 tile, BK=64, 4 waves, global_load_lds 16B staging.
template <bool GELU>
__global__ __launch_bounds__(256, 2) void gemm_bt(const u16* __restrict__ A,
    const u16* __restrict__ Bt, u16* __restrict__ C,
    const float* __restrict__ bias, int M, int N) {
  __shared__ __align__(16) u16 As[128 * 64];
  __shared__ __align__(16) u16 Bs[128 * 64];
  int tid = threadIdx.x;
  int w = tid >> 6, lane = tid & 63;
  int m0 = blockIdx.y << 7, n0 = blockIdx.x << 7;
  int wm = (w & 1) << 6, wn = (w >> 1) << 6;
  f32x4 acc[4][4] = {};
  const int r_off = lane >> 3;        // 0..7 (row within 8-row chunk)
  const int k_off = (lane & 7) << 3;  // 0..56 (f16 col)
  for (int kt = 0; kt < 8; ++kt) {
    __syncthreads();
#pragma unroll
    for (int j = 0; j < 4; ++j) {
      int q = (w << 2) + j;  // chunk 0..15, 8 rows each
      const u16* gA = A + (size_t)(m0 + (q << 3) + r_off) * 512 + (kt << 6) + k_off;
      __builtin_amdgcn_global_load_lds(
          (const __attribute__((address_space(1))) u32*)gA,
          (__attribute__((address_space(3))) u32*)(As + (q << 9)), 16, 0, 0);
      const u16* gB = Bt + (size_t)(n0 + (q << 3) + r_off) * 512 + (kt << 6) + k_off;
      __builtin_amdgcn_global_load_lds(
          (const __attribute__((address_space(1))) u32*)gB,
          (__attribute__((address_space(3))) u32*)(Bs + (q << 9)), 16, 0, 0);
    }
    asm volatile("s_waitcnt vmcnt(0)" ::: "memory");
    __syncthreads();
#pragma unroll
    for (int kk = 0; kk < 2; ++kk) {
      int ko = (kk << 5) + ((lane >> 4) << 3);
      f16x8 af[4], bfr[4];
#pragma unroll
      for (int mi = 0; mi < 4; ++mi)
        af[mi] = *(const f16x8*)(As + (wm + (mi << 4) + (lane & 15)) * 64 + ko);
#pragma unroll
      for (int ni = 0; ni < 4; ++ni)
        bfr[ni] = *(const f16x8*)(Bs + (wn + (ni << 4) + (lane & 15)) * 64 + ko);
#pragma unroll
      for (int mi = 0; mi < 4; ++mi)
#pragma unroll
        for (int ni = 0; ni < 4; ++ni)
          acc[mi][ni] = __builtin_amdgcn_mfma_f32_16x16x32_f16(af[mi], bfr[ni], acc[mi][ni], 0, 0, 0);
    }
  }
  int cr = (lane >> 4) << 2, cc = lane & 15;
#pragma unroll
  for (int mi = 0; mi < 4; ++mi) {
#pragma unroll
    for (int ni = 0; ni < 4; ++ni) {
      int col = n0 + wn + (ni << 4) + cc;
      float bv = 0.f;
      if (GELU) bv = bias[col];
#pragma unroll
      for (int j = 0; j < 4; ++j) {
        int row = m0 + wm + (mi << 4) + cr + j;
        float v = acc[mi][ni][j];
        if (GELU) { v += bv; v = 0.5f * v * (1.f + erff(v * 0.70710678118f)); }
        C[(size_t)row * N + col] = f2h(v);
      }
    }
  }
}

// ---------------- attention: per-batch block ---------------------------------
// Q: (nb*25, 512) f16; KV: (nb*NKV, 1024) f16 [K cols 0..511, V 512..1023]
// 512 threads: h = tid>>6 (8 heads), n = (tid&63)>>1 (row, <25), half = tid&1
// (each lane owns 32 of the 64 head dims; shfl_xor(1) completes dots).
// f16 operands kept packed; (float)h folds into v_fma_mix_f32 (no cvt insts).
// __launch_bounds__(512, 2): 2 blocks/CU -> 128-VGPR budget, no scratch spills
// (the round-3/4 killer: (512,4) capped VGPRs at 64 -> ~50 floats/thread
// spilled to scratch -> GBs of HBM traffic).
template <int NKV, bool INIT>
__global__ __launch_bounds__(512, 2) void attn(const u16* __restrict__ Q,
    const u16* __restrict__ KV, const u16* __restrict__ xb, float* __restrict__ out) {
  __shared__ __align__(16) u16 KVl[NKV * 1024];
  int b = blockIdx.x, tid = threadIdx.x;
  const u16* kvb = KV + (size_t)b * (NKV * 1024);
  for (int e = tid * 8; e < NKV * 1024; e += 4096)
    *(u16x8*)(KVl + e) = *(const u16x8*)(kvb + e);
  __syncthreads();
  int h = tid >> 6, r = tid & 63, n = r >> 1, half = r & 1;
  if (n < 25) {
    int dbase = (h << 6) + (half << 5);
    const u16* qr = Q + (size_t)(b * 25 + n) * 512 + dbase;
    f16x8 q8[4];
#pragma unroll
    for (int i = 0; i < 4; ++i) q8[i] = *(const f16x8*)(qr + (i << 3));
    float s[NKV];
    float mx = -1e30f;
#pragma unroll
    for (int m = 0; m < NKV; ++m) {
      const u16* kr = KVl + m * 1024 + dbase;   // 2 addrs/wave: broadcast, no conflict
      float p = 0.f;
#pragma unroll
      for (int i = 0; i < 4; ++i) {
        f16x8 kv = *(const f16x8*)(kr + (i << 3));
#pragma unroll
        for (int j = 0; j < 8; ++j) p += (float)q8[i][j] * (float)kv[j];
      }
      float d = p + __shfl_xor(p, 1);
      s[m] = d * 0.125f;
      mx = fmaxf(mx, s[m]);
    }
    float sum = 0.f;
#pragma unroll
    for (int m = 0; m < NKV; ++m) { s[m] = __expf(s[m] - mx); sum += s[m]; }
    float o[32] = {};
#pragma unroll
    for (int m = 0; m < NKV; ++m) {
      float a = s[m];
      const u16* vr = KVl + m * 1024 + 512 + dbase;
#pragma unroll
      for (int i = 0; i < 4; ++i) {
        f16x8 vv = *(const f16x8*)(vr + (i << 3));
#pragma unroll
        for (int j = 0; j < 8; ++j) o[i * 8 + j] += a * (float)vv[j];
      }
    }
    float sc = (1.f / sum) * (1.f / 3.f);
    // epilogue: lane-pair (n, half=0/1) covers 256 B contiguous -> full-line HBM
    float* orow = out + (size_t)(b * 25 + n) * 512 + dbase;
    if (INIT) {
      const u16* xrow = xb + (size_t)(b * 25 + n) * 512 + dbase;
#pragma unroll
      for (int i = 0; i < 4; ++i) {
        f16x8 xv = *(const f16x8*)(xrow + (i << 3));
#pragma unroll
        for (int j = 0; j < 8; j += 4) {
          float4 rr;
          rr.x = o[i * 8 + j + 0] * sc + (float)xv[j + 0];
          rr.y = o[i * 8 + j + 1] * sc + (float)xv[j + 1];
          rr.z = o[i * 8 + j + 2] * sc + (float)xv[j + 2];
          rr.w = o[i * 8 + j + 3] * sc + (float)xv[j + 3];
          *(float4*)(orow + i * 8 + j) = rr;
        }
      }
    } else {
#pragma unroll
      for (int i = 0; i < 8; ++i) {
        float4 pv = *(const float4*)(orow + i * 4);
        float4 rr;
        rr.x = o[i * 4 + 0] * sc + pv.x;
        rr.y = o[i * 4 + 1] * sc + pv.y;
        rr.z = o[i * 4 + 2] * sc + pv.z;
        rr.w = o[i * 4 + 3] * sc + pv.w;
        *(float4*)(orow + i * 4) = rr;
      }
    }
  }
}

// ---------------- pool: fc2 + softmax + S^T * l_feat ------------------------
// h: (nb*NIN, 1024) f16 (gelu'd fc1 out); lf: (nb*NIN, 512) f16 raw l_feat
// w2: (1024, NOUT) fp32; out lout: (nb*NOUT, 512) f16
template <int NIN, int NOUT>
__global__ __launch_bounds__(256) void pool(const u16* __restrict__ h,
    const u16* __restrict__ lf, const float* __restrict__ w2,
    const float* __restrict__ b2, u16* __restrict__ lout) {
  __shared__ __align__(16) float W2l[1024 * NOUT];
  __shared__ __align__(16) u16 Xl[NIN * 512];
  __shared__ __align__(16) float Sl[NIN * NOUT];
  int b = blockIdx.x, tid = threadIdx.x;
  for (int e = tid; e < 1024 * NOUT; e += 256) W2l[e] = w2[e];
  for (int e = tid * 8; e < NIN * 512; e += 2048)
    *(u16x8*)(Xl + e) = *(const u16x8*)(lf + (size_t)b * NIN * 512 + e);
  __syncthreads();
  if (tid < NIN * 8) {
    int nn = tid >> 3, sub = tid & 7;
    float p[NOUT] = {};
    const u16* hr = h + (size_t)(b * NIN + nn) * 1024;
    for (int cc = 0; cc < 128; ++cc) {
      int c = sub + (cc << 3);
      float hv = h2f(hr[c]);
#pragma unroll
      for (int s2 = 0; s2 < NOUT; ++s2) p[s2] += hv * W2l[c * NOUT + s2];
    }
#pragma unroll
    for (int s2 = 0; s2 < NOUT; ++s2) {
      p[s2] += __shfl_down(p[s2], 4, 8);
      p[s2] += __shfl_down(p[s2], 2, 8);
      p[s2] += __shfl_down(p[s2], 1, 8);
    }
    if (sub == 0) {
      float mx = -1e30f;
#pragma unroll
      for (int s2 = 0; s2 < NOUT; ++s2) { p[s2] += b2[s2]; mx = fmaxf(mx, p[s2]); }
      float sum = 0.f;
#pragma unroll
      for (int s2 = 0; s2 < NOUT; ++s2) { p[s2] = __expf(p[s2] - mx); sum += p[s2]; }
      float inv = 1.f / sum;
#pragma unroll
      for (int s2 = 0; s2 < NOUT; ++s2) Sl[nn * NOUT + s2] = p[s2] * inv;
    }
  }
  __syncthreads();
  int c0 = tid << 1;
#pragma unroll
  for (int s2 = 0; s2 < NOUT; ++s2) {
    float a0 = 0.f, a1 = 0.f;
#pragma unroll
    for (int nn = 0; nn < NIN; ++nn) {
      float wv = Sl[nn * NOUT + s2];
      a0 += wv * h2f(Xl[nn * 512 + c0]);
      a1 += wv * h2f(Xl[nn * 512 + c0 + 1]);
    }
    u32 pk = (u32)f2h(a0) | ((u32)f2h(a1) << 16);
    *(u32*)(lout + (size_t)(b * NOUT + s2) * 512 + c0) = pk;
  }
}

// ---------------- launcher ---------------------------------------------------
extern "C" void kernel_launch(void* const* d_in, const int* in_sizes, int n_in,
                              void* d_out, int out_size, void* d_ws, size_t ws_size,
                              hipStream_t stream) {
  const float* src = (const float*)d_in[0];
  // d_in[1] spatial_relation: unused (dead in reference output math)
  const float* g    = (const float*)d_in[2];
  const float* bt   = (const float*)d_in[3];
  const float* Wq   = (const float*)d_in[4];
  const float* Wk   = (const float*)d_in[5];
  const float* Wv   = (const float*)d_in[6];
  const float* f0w  = (const float*)d_in[7];
  const float* f0b  = (const float*)d_in[8];
  const float* f0w2 = (const float*)d_in[9];
  const float* f0b2 = (const float*)d_in[10];
  const float* f1w  = (const float*)d_in[11];
  const float* f1b  = (const float*)d_in[12];
  const float* f1w2 = (const float*)d_in[13];
  const float* f1b2 = (const float*)d_in[14];
  float* out = (float*)d_out;
  char* ws = (char*)d_ws;

  // workspace layout (bytes), peak ~503 MB (validated round 2)
  u16* wt  = (u16*)(ws + 0);
  u16* xn  = (u16*)(ws + 6815744);
  u16* xb  = (u16*)(ws + 111673344);
  u16* qb  = (u16*)(ws + 216530944);
  u16* B1  = (u16*)(ws + 321388544);
  u16* l1  = (u16*)(ws + 426246144);
  u16* kn1 = (u16*)(ws + 476577792);
  u16* l2  = qb;                       // 28 MB, alive pool1->ln only
  u16* kn2 = qb + 14680064;            // alive ln->KV2 gemm only

  prep_w<<<13312, 256, 0, stream>>>(Wq, Wk, Wv, f0w, f1w, wt);
  ln_f32<<<25600, 256, 0, stream>>>(src, g, bt, xn, xb);

  // scale 0: Q gemm full, KV gemm + attn in 2 half-slices sharing B1 (100 MB)
  gemm_bt<false><<<dim3(4, 800), 256, 0, stream>>>(xn, wt, qb, nullptr, 102400, 512);
  for (int s = 0; s < 2; ++s) {
    size_t ro = (size_t)s * 51200;   // row offset (2048 batches)
    gemm_bt<false><<<dim3(8, 400), 256, 0, stream>>>(xn + ro * 512, wt + 786432, B1, nullptr, 51200, 1024);
    attn<25, true><<<2048, 512, 0, stream>>>(qb + ro * 512, B1, xb + ro * 512, out + ro * 512);
  }

  // pool 0: fc1(gelu) gemm + pool in 2 half-slices, h half lives in B1
  for (int s = 0; s < 2; ++s) {
    size_t ro = (size_t)s * 51200;
    gemm_bt<true><<<dim3(8, 400), 256, 0, stream>>>(xb + ro * 512, wt + 2359296, B1, f0b, 51200, 1024);
    pool<25, 12><<<2048, 256, 0, stream>>>(B1, xb + ro * 512, f0w2, f0b2, l1 + (size_t)s * 2048 * 12 * 512);
  }
  ln_b16<<<12288, 256, 0, stream>>>(l1, g, bt, kn1);

  // scale 1
  gemm_bt<false><<<dim3(4, 800), 256, 0, stream>>>(xn, wt + 262144, qb, nullptr, 102400, 512);
  gemm_bt<false><<<dim3(8, 384), 256, 0, stream>>>(kn1, wt + 786432 + 524288, B1, nullptr, 49152, 1024);
  attn<12, false><<<4096, 512, 0, stream>>>(qb, B1, nullptr, out);

  // pool 1: h1 (96 MB) in B1 after attn1
  gemm_bt<true><<<dim3(8, 384), 256, 0, stream>>>(l1, wt + 2883584, B1, f1b, 49152, 1024);
  pool<12, 7><<<4096, 256, 0, stream>>>(B1, l1, f1w2, f1b2, l2);
  ln_b16<<<7168, 256, 0, stream>>>(l2, g, bt, kn2);

  // scale 2: KV gemm BEFORE Q gemm (kn2 lives in qb region; Q2 gemm clobbers it)
  gemm_bt<false><<<dim3(8, 224), 256, 0, stream>>>(kn2, wt + 786432 + 1048576, B1, nullptr, 28672, 1024);
  gemm_bt<false><<<dim3(4, 800), 256, 0, stream>>>(xn, wt + 524288, qb, nullptr, 102400, 512);
  attn<7, false><<<4096, 512, 0, stream>>>(qb, B1, nullptr, out);
}

// Round 7
// 1772.651 us; speedup vs baseline: 2.1178x; 1.0210x over previous
//
#include <hip/hip_runtime.h>

typedef unsigned short u16;
typedef unsigned int   u32;
typedef _Float16 f16;
typedef __attribute__((ext_vector_type(8))) unsigned short u16x8;
typedef __attribute__((ext_vector_type(8))) _Float16 f16x8;
typedef __attribute__((ext_vector_type(4))) float f32x4;

__device__ __forceinline__ u16 f2h(float f) {
  f16 h = (f16)f;
  return __builtin_bit_cast(u16, h);
}
__device__ __forceinline__ float h2f(u16 u) {
  return (float)__builtin_bit_cast(f16, u);
}

// ---------------- weight prep: transpose to (N x K) row-major + cvt f16 -----
// wt layout (elements):
//   [0..786432)        : WqT[3]   (3 x 512x512), WqT[i] at i*262144
//   [786432..2359296)  : (WkT,WvT)[3] pairs: kv_i at 786432+i*524288 (K rows 0..511, V rows 512..1023)
//   [2359296..2883584) : f0T (1024x512)
//   [2883584..3407872) : f1T (1024x512)
__global__ __launch_bounds__(256) void prep_w(const float* __restrict__ Wq,
    const float* __restrict__ Wk, const float* __restrict__ Wv,
    const float* __restrict__ f0, const float* __restrict__ f1,
    u16* __restrict__ wt) {
  int t = blockIdx.x * 256 + threadIdx.x;
  float v;
  if (t < 786432) {
    int i = t >> 18, r = t & 262143, n = r >> 9, k = r & 511;
    v = Wq[(size_t)(i << 18) + k * 512 + n];
  } else if (t < 2359296) {
    int r = t - 786432, i = r >> 19, r2 = r & 524287;
    int n = (r2 >> 9) & 511, k = r2 & 511;
    v = ((r2 >> 18) ? Wv : Wk)[(size_t)(i << 18) + k * 512 + n];
  } else if (t < 2883584) {
    int r = t - 2359296, n = r >> 9, k = r & 511;
    v = f0[(size_t)k * 1024 + n];
  } else {
    int r = t - 2883584, n = r >> 9, k = r & 511;
    v = f1[(size_t)k * 1024 + n];
  }
  wt[t] = f2h(v);
}

// ---------------- LayerNorm (fp32 in) -> xn f16, xb f16(raw) ----------------
__global__ __launch_bounds__(256) void ln_f32(const float* __restrict__ x,
    const float* __restrict__ g, const float* __restrict__ bta,
    u16* __restrict__ xn, u16* __restrict__ xb) {
  int row = (blockIdx.x << 2) + (threadIdx.x >> 6);
  int lane = threadIdx.x & 63;
  const float* xr = x + (size_t)row * 512 + (lane << 3);
  float4 a = *(const float4*)xr;
  float4 c = *(const float4*)(xr + 4);
  float v[8] = {a.x, a.y, a.z, a.w, c.x, c.y, c.z, c.w};
  float s = 0.f, s2 = 0.f;
#pragma unroll
  for (int j = 0; j < 8; ++j) { s += v[j]; s2 += v[j] * v[j]; }
  for (int off = 32; off; off >>= 1) { s += __shfl_xor(s, off); s2 += __shfl_xor(s2, off); }
  float mean = s * (1.f / 512.f);
  float var = s2 * (1.f / 512.f) - mean * mean;
  float rs = rsqrtf(var + 1e-5f);
  const float* gp = g + (lane << 3);
  const float* bp = bta + (lane << 3);
  u16x8 pb, pn;
#pragma unroll
  for (int j = 0; j < 8; ++j) {
    pb[j] = f2h(v[j]);
    pn[j] = f2h((v[j] - mean) * rs * gp[j] + bp[j]);
  }
  *(u16x8*)(xb + (size_t)row * 512 + (lane << 3)) = pb;
  *(u16x8*)(xn + (size_t)row * 512 + (lane << 3)) = pn;
}

// ---------------- LayerNorm (f16 in) -> f16 out -----------------------------
__global__ __launch_bounds__(256) void ln_b16(const u16* __restrict__ xin,
    const float* __restrict__ g, const float* __restrict__ bta,
    u16* __restrict__ xout) {
  int row = (blockIdx.x << 2) + (threadIdx.x >> 6);
  int lane = threadIdx.x & 63;
  f16x8 u = *(const f16x8*)(xin + (size_t)row * 512 + (lane << 3));
  float v[8];
#pragma unroll
  for (int j = 0; j < 8; ++j) v[j] = (float)u[j];
  float s = 0.f, s2 = 0.f;
#pragma unroll
  for (int j = 0; j < 8; ++j) { s += v[j]; s2 += v[j] * v[j]; }
  for (int off = 32; off; off >>= 1) { s += __shfl_xor(s, off); s2 += __shfl_xor(s2, off); }
  float mean = s * (1.f / 512.f);
  float var = s2 * (1.f / 512.f) - mean * mean;
  float rs = rsqrtf(var + 1e-5f);
  const float* gp = g + (lane << 3);
  const float* bp = bta + (lane << 3);
  u16x8 pn;
#pragma unroll
  for (int j = 0; j < 8; ++j) pn[j] = f2h((v[j] - mean) * rs * gp[j] + bp[j]);
  *(u16x8*)(xout + (size_t)row * 512 + (lane << 3)) = pn;
}

// ---------------- GEMM: C(MxN f16) = A(Mx512 f16) * Bt(Nx512 f16)^T ---------
// m97-style 128x128 tile, BK=64, 4 waves, global_load_lds 16B staging.
template <bool GELU>
__global__ __launch_bounds__(256, 2) void gemm_bt(const u16* __restrict__ A,
    const u16* __restrict__ Bt, u16* __restrict__ C,
    const float* __restrict__ bias, int M, int N) {
  __shared__ __align__(16) u16 As[128 * 64];
  __shared__ __align__(16) u16 Bs[128 * 64];
  int tid = threadIdx.x;
  int w = tid >> 6, lane = tid & 63;
  int m0 = blockIdx.y << 7, n0 = blockIdx.x << 7;
  int wm = (w & 1) << 6, wn = (w >> 1) << 6;
  f32x4 acc[4][4] = {};
  const int r_off = lane >> 3;        // 0..7 (row within 8-row chunk)
  const int k_off = (lane & 7) << 3;  // 0..56 (f16 col)
  for (int kt = 0; kt < 8; ++kt) {
    __syncthreads();
#pragma unroll
    for (int j = 0; j < 4; ++j) {
      int q = (w << 2) + j;  // chunk 0..15, 8 rows each
      const u16* gA = A + (size_t)(m0 + (q << 3) + r_off) * 512 + (kt << 6) + k_off;
      __builtin_amdgcn_global_load_lds(
          (const __attribute__((address_space(1))) u32*)gA,
          (__attribute__((address_space(3))) u32*)(As + (q << 9)), 16, 0, 0);
      const u16* gB = Bt + (size_t)(n0 + (q << 3) + r_off) * 512 + (kt << 6) + k_off;
      __builtin_amdgcn_global_load_lds(
          (const __attribute__((address_space(1))) u32*)gB,
          (__attribute__((address_space(3))) u32*)(Bs + (q << 9)), 16, 0, 0);
    }
    asm volatile("s_waitcnt vmcnt(0)" ::: "memory");
    __syncthreads();
#pragma unroll
    for (int kk = 0; kk < 2; ++kk) {
      int ko = (kk << 5) + ((lane >> 4) << 3);
      f16x8 af[4], bfr[4];
#pragma unroll
      for (int mi = 0; mi < 4; ++mi)
        af[mi] = *(const f16x8*)(As + (wm + (mi << 4) + (lane & 15)) * 64 + ko);
#pragma unroll
      for (int ni = 0; ni < 4; ++ni)
        bfr[ni] = *(const f16x8*)(Bs + (wn + (ni << 4) + (lane & 15)) * 64 + ko);
#pragma unroll
      for (int mi = 0; mi < 4; ++mi)
#pragma unroll
        for (int ni = 0; ni < 4; ++ni)
          acc[mi][ni] = __builtin_amdgcn_mfma_f32_16x16x32_f16(af[mi], bfr[ni], acc[mi][ni], 0, 0, 0);
    }
  }
  int cr = (lane >> 4) << 2, cc = lane & 15;
#pragma unroll
  for (int mi = 0; mi < 4; ++mi) {
#pragma unroll
    for (int ni = 0; ni < 4; ++ni) {
      int col = n0 + wn + (ni << 4) + cc;
      float bv = 0.f;
      if (GELU) bv = bias[col];
#pragma unroll
      for (int j = 0; j < 4; ++j) {
        int row = m0 + wm + (mi << 4) + cr + j;
        float v = acc[mi][ni][j];
        if (GELU) { v += bv; v = 0.5f * v * (1.f + erff(v * 0.70710678118f)); }
        C[(size_t)row * N + col] = f2h(v);
      }
    }
  }
}

// ---------------- attention: G batches per block, double-buffered KV --------
// Q: (nb*25, 512) f16; KV: (nb*NKV, 1024) f16 [K cols 0..511, V 512..1023]
// 512 threads: h = tid>>6 (8 heads), n = (tid&63)>>1 (row, <25), half = tid&1.
// 2-phase pipeline: stage KV(t+1) via global_load_lds -> compute(t) ->
// vmcnt(0)+barrier -> swap. HBM latency of the stage hides under compute
// (round-6 lesson: single-shot blocks were latency-bound at 2.2 TB/s).
// MINW: launch_bounds min-waves arg (VGPR cap 512/MINW/... ): 25 -> 1 (100KB
// LDS forces 1 blk/CU anyway), 12/7 -> 2 (128-VGPR cap, fits, 2 blk/CU).
template <int NKV, bool INIT, int MINW>
__global__ __launch_bounds__(512, MINW) void attn(const u16* __restrict__ Q,
    const u16* __restrict__ KV, const u16* __restrict__ xb, float* __restrict__ out) {
  constexpr int G = 8;
  constexpr int ELEMS = NKV * 1024;          // u16 per batch
  __shared__ __align__(16) u16 KVl[2][ELEMS];
  int tid = threadIdx.x;
  int b0 = blockIdx.x * G;
  int h = tid >> 6, r = tid & 63, n = r >> 1, half = r & 1;
  int dbase = (h << 6) + (half << 5);
  // prologue: stage batch 0 into buf 0
  {
    const u16* src = KV + (size_t)b0 * ELEMS;
    for (int e = tid * 8; e < ELEMS; e += 4096)   // wave-uniform guard
      __builtin_amdgcn_global_load_lds(
          (const __attribute__((address_space(1))) u32*)(src + e),
          (__attribute__((address_space(3))) u32*)(KVl[0] + e), 16, 0, 0);
  }
  asm volatile("s_waitcnt vmcnt(0)" ::: "memory");
  __syncthreads();
  for (int t = 0; t < G; ++t) {
    const u16* KVc = KVl[t & 1];
    if (t + 1 < G) {                              // issue next stage (async)
      const u16* src = KV + (size_t)(b0 + t + 1) * ELEMS;
      u16* dst = KVl[(t + 1) & 1];
      for (int e = tid * 8; e < ELEMS; e += 4096)
        __builtin_amdgcn_global_load_lds(
            (const __attribute__((address_space(1))) u32*)(src + e),
            (__attribute__((address_space(3))) u32*)(dst + e), 16, 0, 0);
    }
    int b = b0 + t;
    if (n < 25) {
      const u16* qr = Q + (size_t)(b * 25 + n) * 512 + dbase;
      f16x8 q8[4];
#pragma unroll
      for (int i = 0; i < 4; ++i) q8[i] = *(const f16x8*)(qr + (i << 3));
      float s[NKV];
      float mx = -1e30f;
#pragma unroll
      for (int m = 0; m < NKV; ++m) {
        const u16* kr = KVc + m * 1024 + dbase;   // 2 addrs/wave: broadcast
        float p = 0.f;
#pragma unroll
        for (int i = 0; i < 4; ++i) {
          f16x8 kv = *(const f16x8*)(kr + (i << 3));
#pragma unroll
          for (int j = 0; j < 8; ++j) p += (float)q8[i][j] * (float)kv[j];
        }
        float d = p + __shfl_xor(p, 1);
        s[m] = d * 0.125f;
        mx = fmaxf(mx, s[m]);
      }
      float sum = 0.f;
#pragma unroll
      for (int m = 0; m < NKV; ++m) { s[m] = __expf(s[m] - mx); sum += s[m]; }
      float o[32] = {};
#pragma unroll
      for (int m = 0; m < NKV; ++m) {
        float a = s[m];
        const u16* vr = KVc + m * 1024 + 512 + dbase;
#pragma unroll
        for (int i = 0; i < 4; ++i) {
          f16x8 vv = *(const f16x8*)(vr + (i << 3));
#pragma unroll
          for (int j = 0; j < 8; ++j) o[i * 8 + j] += a * (float)vv[j];
        }
      }
      float sc = (1.f / sum) * (1.f / 3.f);
      // epilogue: lane-pair (n, half=0/1) covers 256 B contiguous
      float* orow = out + (size_t)(b * 25 + n) * 512 + dbase;
      if (INIT) {
        const u16* xrow = xb + (size_t)(b * 25 + n) * 512 + dbase;
#pragma unroll
        for (int i = 0; i < 4; ++i) {
          f16x8 xv = *(const f16x8*)(xrow + (i << 3));
#pragma unroll
          for (int j = 0; j < 8; j += 4) {
            float4 rr;
            rr.x = o[i * 8 + j + 0] * sc + (float)xv[j + 0];
            rr.y = o[i * 8 + j + 1] * sc + (float)xv[j + 1];
            rr.z = o[i * 8 + j + 2] * sc + (float)xv[j + 2];
            rr.w = o[i * 8 + j + 3] * sc + (float)xv[j + 3];
            *(float4*)(orow + i * 8 + j) = rr;
          }
        }
      } else {
#pragma unroll
        for (int i = 0; i < 8; ++i) {
          float4 pv = *(const float4*)(orow + i * 4);
          float4 rr;
          rr.x = o[i * 4 + 0] * sc + pv.x;
          rr.y = o[i * 4 + 1] * sc + pv.y;
          rr.z = o[i * 4 + 2] * sc + pv.z;
          rr.w = o[i * 4 + 3] * sc + pv.w;
          *(float4*)(orow + i * 4) = rr;
        }
      }
    }
    asm volatile("s_waitcnt vmcnt(0)" ::: "memory");  // staged loads landed
    __syncthreads();
  }
}

// ---------------- pool: fc2 + softmax + S^T * l_feat ------------------------
// h: (nb*NIN, 1024) f16 (gelu'd fc1 out); lf: (nb*NIN, 512) f16 raw l_feat
// w2: (1024, NOUT) fp32; out lout: (nb*NOUT, 512) f16
template <int NIN, int NOUT>
__global__ __launch_bounds__(256) void pool(const u16* __restrict__ h,
    const u16* __restrict__ lf, const float* __restrict__ w2,
    const float* __restrict__ b2, u16* __restrict__ lout) {
  __shared__ __align__(16) float W2l[1024 * NOUT];
  __shared__ __align__(16) u16 Xl[NIN * 512];
  __shared__ __align__(16) float Sl[NIN * NOUT];
  int b = blockIdx.x, tid = threadIdx.x;
  for (int e = tid; e < 1024 * NOUT; e += 256) W2l[e] = w2[e];
  for (int e = tid * 8; e < NIN * 512; e += 2048)
    *(u16x8*)(Xl + e) = *(const u16x8*)(lf + (size_t)b * NIN * 512 + e);
  __syncthreads();
  if (tid < NIN * 8) {
    int nn = tid >> 3, sub = tid & 7;
    float p[NOUT] = {};
    const u16* hr = h + (size_t)(b * NIN + nn) * 1024;
    for (int cc = 0; cc < 128; ++cc) {
      int c = sub + (cc << 3);
      float hv = h2f(hr[c]);
#pragma unroll
      for (int s2 = 0; s2 < NOUT; ++s2) p[s2] += hv * W2l[c * NOUT + s2];
    }
#pragma unroll
    for (int s2 = 0; s2 < NOUT; ++s2) {
      p[s2] += __shfl_down(p[s2], 4, 8);
      p[s2] += __shfl_down(p[s2], 2, 8);
      p[s2] += __shfl_down(p[s2], 1, 8);
    }
    if (sub == 0) {
      float mx = -1e30f;
#pragma unroll
      for (int s2 = 0; s2 < NOUT; ++s2) { p[s2] += b2[s2]; mx = fmaxf(mx, p[s2]); }
      float sum = 0.f;
#pragma unroll
      for (int s2 = 0; s2 < NOUT; ++s2) { p[s2] = __expf(p[s2] - mx); sum += p[s2]; }
      float inv = 1.f / sum;
#pragma unroll
      for (int s2 = 0; s2 < NOUT; ++s2) Sl[nn * NOUT + s2] = p[s2] * inv;
    }
  }
  __syncthreads();
  int c0 = tid << 1;
#pragma unroll
  for (int s2 = 0; s2 < NOUT; ++s2) {
    float a0 = 0.f, a1 = 0.f;
#pragma unroll
    for (int nn = 0; nn < NIN; ++nn) {
      float wv = Sl[nn * NOUT + s2];
      a0 += wv * h2f(Xl[nn * 512 + c0]);
      a1 += wv * h2f(Xl[nn * 512 + c0 + 1]);
    }
    u32 pk = (u32)f2h(a0) | ((u32)f2h(a1) << 16);
    *(u32*)(lout + (size_t)(b * NOUT + s2) * 512 + c0) = pk;
  }
}

// ---------------- launcher ---------------------------------------------------
extern "C" void kernel_launch(void* const* d_in, const int* in_sizes, int n_in,
                              void* d_out, int out_size, void* d_ws, size_t ws_size,
                              hipStream_t stream) {
  const float* src = (const float*)d_in[0];
  // d_in[1] spatial_relation: unused (dead in reference output math)
  const float* g    = (const float*)d_in[2];
  const float* bt   = (const float*)d_in[3];
  const float* Wq   = (const float*)d_in[4];
  const float* Wk   = (const float*)d_in[5];
  const float* Wv   = (const float*)d_in[6];
  const float* f0w  = (const float*)d_in[7];
  const float* f0b  = (const float*)d_in[8];
  const float* f0w2 = (const float*)d_in[9];
  const float* f0b2 = (const float*)d_in[10];
  const float* f1w  = (const float*)d_in[11];
  const float* f1b  = (const float*)d_in[12];
  const float* f1w2 = (const float*)d_in[13];
  const float* f1b2 = (const float*)d_in[14];
  float* out = (float*)d_out;
  char* ws = (char*)d_ws;

  // workspace layout (bytes), peak ~503 MB (validated round 2)
  u16* wt  = (u16*)(ws + 0);
  u16* xn  = (u16*)(ws + 6815744);
  u16* xb  = (u16*)(ws + 111673344);
  u16* qb  = (u16*)(ws + 216530944);
  u16* B1  = (u16*)(ws + 321388544);
  u16* l1  = (u16*)(ws + 426246144);
  u16* kn1 = (u16*)(ws + 476577792);
  u16* l2  = qb;                       // 28 MB, alive pool1->ln only
  u16* kn2 = qb + 14680064;            // alive ln->KV2 gemm only

  prep_w<<<13312, 256, 0, stream>>>(Wq, Wk, Wv, f0w, f1w, wt);
  ln_f32<<<25600, 256, 0, stream>>>(src, g, bt, xn, xb);

  // scale 0: Q gemm full, KV gemm + attn in 2 half-slices sharing B1 (100 MB)
  gemm_bt<false><<<dim3(4, 800), 256, 0, stream>>>(xn, wt, qb, nullptr, 102400, 512);
  for (int s = 0; s < 2; ++s) {
    size_t ro = (size_t)s * 51200;   // row offset (2048 batches)
    gemm_bt<false><<<dim3(8, 400), 256, 0, stream>>>(xn + ro * 512, wt + 786432, B1, nullptr, 51200, 1024);
    attn<25, true, 1><<<256, 512, 0, stream>>>(qb + ro * 512, B1, xb + ro * 512, out + ro * 512);
  }

  // pool 0: fc1(gelu) gemm + pool in 2 half-slices, h half lives in B1
  for (int s = 0; s < 2; ++s) {
    size_t ro = (size_t)s * 51200;
    gemm_bt<true><<<dim3(8, 400), 256, 0, stream>>>(xb + ro * 512, wt + 2359296, B1, f0b, 51200, 1024);
    pool<25, 12><<<2048, 256, 0, stream>>>(B1, xb + ro * 512, f0w2, f0b2, l1 + (size_t)s * 2048 * 12 * 512);
  }
  ln_b16<<<12288, 256, 0, stream>>>(l1, g, bt, kn1);

  // scale 1
  gemm_bt<false><<<dim3(4, 800), 256, 0, stream>>>(xn, wt + 262144, qb, nullptr, 102400, 512);
  gemm_bt<false><<<dim3(8, 384), 256, 0, stream>>>(kn1, wt + 786432 + 524288, B1, nullptr, 49152, 1024);
  attn<12, false, 2><<<512, 512, 0, stream>>>(qb, B1, nullptr, out);

  // pool 1: h1 (96 MB) in B1 after attn1
  gemm_bt<true><<<dim3(8, 384), 256, 0, stream>>>(l1, wt + 2883584, B1, f1b, 49152, 1024);
  pool<12, 7><<<4096, 256, 0, stream>>>(B1, l1, f1w2, f1b2, l2);
  ln_b16<<<7168, 256, 0, stream>>>(l2, g, bt, kn2);

  // scale 2: KV gemm BEFORE Q gemm (kn2 lives in qb region; Q2 gemm clobbers it)
  gemm_bt<false><<<dim3(8, 224), 256, 0, stream>>>(kn2, wt + 786432 + 1048576, B1, nullptr, 28672, 1024);
  gemm_bt<false><<<dim3(4, 800), 256, 0, stream>>>(xn, wt + 524288, qb, nullptr, 102400, 512);
  attn<7, false, 2><<<512, 512, 0, stream>>>(qb, B1, nullptr, out);
}

// Round 8
// 1569.354 us; speedup vs baseline: 2.3921x; 1.1295x over previous
//
#include <hip/hip_runtime.h>

typedef unsigned short u16;
typedef unsigned int   u32;
typedef _Float16 f16;
typedef __attribute__((ext_vector_type(8))) unsigned short u16x8;
typedef __attribute__((ext_vector_type(8))) _Float16 f16x8;
typedef __attribute__((ext_vector_type(2))) _Float16 f16x2;
typedef __attribute__((ext_vector_type(4))) float f32x4;

__device__ __forceinline__ u16 f2h(float f) {
  f16 h = (f16)f;
  return __builtin_bit_cast(u16, h);
}
__device__ __forceinline__ float h2f(u16 u) {
  return (float)__builtin_bit_cast(f16, u);
}

// ---------------- weight prep: transpose to (N x K) row-major + cvt f16 -----
__global__ __launch_bounds__(256) void prep_w(const float* __restrict__ Wq,
    const float* __restrict__ Wk, const float* __restrict__ Wv,
    const float* __restrict__ f0, const float* __restrict__ f1,
    u16* __restrict__ wt) {
  int t = blockIdx.x * 256 + threadIdx.x;
  float v;
  if (t < 786432) {
    int i = t >> 18, r = t & 262143, n = r >> 9, k = r & 511;
    v = Wq[(size_t)(i << 18) + k * 512 + n];
  } else if (t < 2359296) {
    int r = t - 786432, i = r >> 19, r2 = r & 524287;
    int n = (r2 >> 9) & 511, k = r2 & 511;
    v = ((r2 >> 18) ? Wv : Wk)[(size_t)(i << 18) + k * 512 + n];
  } else if (t < 2883584) {
    int r = t - 2359296, n = r >> 9, k = r & 511;
    v = f0[(size_t)k * 1024 + n];
  } else {
    int r = t - 2883584, n = r >> 9, k = r & 511;
    v = f1[(size_t)k * 1024 + n];
  }
  wt[t] = f2h(v);
}

// ---------------- LayerNorm (fp32 in) -> xn f16, xb f16(raw) ----------------
__global__ __launch_bounds__(256) void ln_f32(const float* __restrict__ x,
    const float* __restrict__ g, const float* __restrict__ bta,
    u16* __restrict__ xn, u16* __restrict__ xb) {
  int row = (blockIdx.x << 2) + (threadIdx.x >> 6);
  int lane = threadIdx.x & 63;
  const float* xr = x + (size_t)row * 512 + (lane << 3);
  float4 a = *(const float4*)xr;
  float4 c = *(const float4*)(xr + 4);
  float v[8] = {a.x, a.y, a.z, a.w, c.x, c.y, c.z, c.w};
  float s = 0.f, s2 = 0.f;
#pragma unroll
  for (int j = 0; j < 8; ++j) { s += v[j]; s2 += v[j] * v[j]; }
  for (int off = 32; off; off >>= 1) { s += __shfl_xor(s, off); s2 += __shfl_xor(s2, off); }
  float mean = s * (1.f / 512.f);
  float var = s2 * (1.f / 512.f) - mean * mean;
  float rs = rsqrtf(var + 1e-5f);
  const float* gp = g + (lane << 3);
  const float* bp = bta + (lane << 3);
  u16x8 pb, pn;
#pragma unroll
  for (int j = 0; j < 8; ++j) {
    pb[j] = f2h(v[j]);
    pn[j] = f2h((v[j] - mean) * rs * gp[j] + bp[j]);
  }
  *(u16x8*)(xb + (size_t)row * 512 + (lane << 3)) = pb;
  *(u16x8*)(xn + (size_t)row * 512 + (lane << 3)) = pn;
}

// ---------------- LayerNorm (f16 in) -> f16 out -----------------------------
__global__ __launch_bounds__(256) void ln_b16(const u16* __restrict__ xin,
    const float* __restrict__ g, const float* __restrict__ bta,
    u16* __restrict__ xout) {
  int row = (blockIdx.x << 2) + (threadIdx.x >> 6);
  int lane = threadIdx.x & 63;
  f16x8 u = *(const f16x8*)(xin + (size_t)row * 512 + (lane << 3));
  float v[8];
#pragma unroll
  for (int j = 0; j < 8; ++j) v[j] = (float)u[j];
  float s = 0.f, s2 = 0.f;
#pragma unroll
  for (int j = 0; j < 8; ++j) { s += v[j]; s2 += v[j] * v[j]; }
  for (int off = 32; off; off >>= 1) { s += __shfl_xor(s, off); s2 += __shfl_xor(s2, off); }
  float mean = s * (1.f / 512.f);
  float var = s2 * (1.f / 512.f) - mean * mean;
  float rs = rsqrtf(var + 1e-5f);
  const float* gp = g + (lane << 3);
  const float* bp = bta + (lane << 3);
  u16x8 pn;
#pragma unroll
  for (int j = 0; j < 8; ++j) pn[j] = f2h((v[j] - mean) * rs * gp[j] + bp[j]);
  *(u16x8*)(xout + (size_t)row * 512 + (lane << 3)) = pn;
}

// ---------------- GEMM: C(MxN f16) = A(Mx512 f16) * Bt(Nx512 f16)^T ---------
// m97-style 128x128 tile, BK=64, 4 waves, global_load_lds 16B staging.
// XCD bijective swizzle (all launched grids have nwg % 8 == 0).
template <bool GELU>
__global__ __launch_bounds__(256, 2) void gemm_bt(const u16* __restrict__ A,
    const u16* __restrict__ Bt, u16* __restrict__ C,
    const float* __restrict__ bias, int M, int N) {
  __shared__ __align__(16) u16 As[128 * 64];
  __shared__ __align__(16) u16 Bs[128 * 64];
  int tid = threadIdx.x;
  int w = tid >> 6, lane = tid & 63;
  int nwg = gridDim.x * gridDim.y;
  int wg = blockIdx.x + gridDim.x * blockIdx.y;
  int swz = (wg & 7) * (nwg >> 3) + (wg >> 3);
  int m0 = (swz / gridDim.x) << 7, n0 = (swz % gridDim.x) << 7;
  int wm = (w & 1) << 6, wn = (w >> 1) << 6;
  f32x4 acc[4][4] = {};
  const int r_off = lane >> 3;
  const int k_off = (lane & 7) << 3;
  for (int kt = 0; kt < 8; ++kt) {
    __syncthreads();
#pragma unroll
    for (int j = 0; j < 4; ++j) {
      int q = (w << 2) + j;
      const u16* gA = A + (size_t)(m0 + (q << 3) + r_off) * 512 + (kt << 6) + k_off;
      __builtin_amdgcn_global_load_lds(
          (const __attribute__((address_space(1))) u32*)gA,
          (__attribute__((address_space(3))) u32*)(As + (q << 9)), 16, 0, 0);
      const u16* gB = Bt + (size_t)(n0 + (q << 3) + r_off) * 512 + (kt << 6) + k_off;
      __builtin_amdgcn_global_load_lds(
          (const __attribute__((address_space(1))) u32*)gB,
          (__attribute__((address_space(3))) u32*)(Bs + (q << 9)), 16, 0, 0);
    }
    asm volatile("s_waitcnt vmcnt(0)" ::: "memory");
    __syncthreads();
#pragma unroll
    for (int kk = 0; kk < 2; ++kk) {
      int ko = (kk << 5) + ((lane >> 4) << 3);
      f16x8 af[4], bfr[4];
#pragma unroll
      for (int mi = 0; mi < 4; ++mi)
        af[mi] = *(const f16x8*)(As + (wm + (mi << 4) + (lane & 15)) * 64 + ko);
#pragma unroll
      for (int ni = 0; ni < 4; ++ni)
        bfr[ni] = *(const f16x8*)(Bs + (wn + (ni << 4) + (lane & 15)) * 64 + ko);
#pragma unroll
      for (int mi = 0; mi < 4; ++mi)
#pragma unroll
        for (int ni = 0; ni < 4; ++ni)
          acc[mi][ni] = __builtin_amdgcn_mfma_f32_16x16x32_f16(af[mi], bfr[ni], acc[mi][ni], 0, 0, 0);
    }
  }
  int cr = (lane >> 4) << 2, cc = lane & 15;
#pragma unroll
  for (int mi = 0; mi < 4; ++mi) {
#pragma unroll
    for (int ni = 0; ni < 4; ++ni) {
      int col = n0 + wn + (ni << 4) + cc;
      float bv = 0.f;
      if (GELU) bv = bias[col];
#pragma unroll
      for (int j = 0; j < 4; ++j) {
        int row = m0 + wm + (mi << 4) + cr + j;
        float v = acc[mi][ni][j];
        if (GELU) { v += bv; v = 0.5f * v * (1.f + erff(v * 0.70710678118f)); }
        C[(size_t)row * N + col] = f2h(v);
      }
    }
  }
}

// ---------------- attention: G batches/block, dbuf KV, packed-f16 math ------
// Q: (nb*25, 512) f16; KV: (nb*NKV, 1024) f16 [K cols 0..511, V 512..1023]
// 512 threads: h = tid>>6, n = (tid&63)>>1 (<25), half = tid&1 (32 dims each).
// QK and PV use f16x2 packed math -> v_pk_fma_f16 (2 FMA/inst; round-7 was
// VALU-heavy at 39% with scalar fma_mix). Softmax weights exp(s-mx) in f32.
// PMODE: 0 = out  = xb + o/(3 sum)          (fp32 out, init)
//        1 = out += o/(3 sum)               (fp32 out, accum)
//        2 = p    = o/sum                   (f16 partial, init)
//        3 = p   += o/sum                   (f16 partial, accum)
//        4 = out  = xb + (p + o/sum)/3      (final combine)
template <int NKV, int PMODE, int MINW>
__global__ __launch_bounds__(512, MINW) void attn(const u16* __restrict__ Q,
    const u16* __restrict__ KV, const u16* __restrict__ xb,
    float* __restrict__ out, u16* __restrict__ p) {
  constexpr int G = 8;
  constexpr int ELEMS = NKV * 1024;
  __shared__ __align__(16) u16 KVl[2][ELEMS];
  int tid = threadIdx.x;
  int b0 = blockIdx.x * G;
  int h = tid >> 6, r = tid & 63, n = r >> 1, half = r & 1;
  int dbase = (h << 6) + (half << 5);
  {
    const u16* src = KV + (size_t)b0 * ELEMS;
    for (int e = tid * 8; e < ELEMS; e += 4096)
      __builtin_amdgcn_global_load_lds(
          (const __attribute__((address_space(1))) u32*)(src + e),
          (__attribute__((address_space(3))) u32*)(KVl[0] + e), 16, 0, 0);
  }
  asm volatile("s_waitcnt vmcnt(0)" ::: "memory");
  __syncthreads();
  for (int t = 0; t < G; ++t) {
    const u16* KVc = KVl[t & 1];
    if (t + 1 < G) {
      const u16* src = KV + (size_t)(b0 + t + 1) * ELEMS;
      u16* dst = KVl[(t + 1) & 1];
      for (int e = tid * 8; e < ELEMS; e += 4096)
        __builtin_amdgcn_global_load_lds(
            (const __attribute__((address_space(1))) u32*)(src + e),
            (__attribute__((address_space(3))) u32*)(dst + e), 16, 0, 0);
    }
    int b = b0 + t;
    if (n < 25) {
      const u16* qr = Q + (size_t)(b * 25 + n) * 512 + dbase;
      f16x8 q8[4];
#pragma unroll
      for (int i = 0; i < 4; ++i) q8[i] = *(const f16x8*)(qr + (i << 3));
      const f16x2* q2 = (const f16x2*)q8;           // 16 packed pairs
      float s[NKV];
      float mx = -1e30f;
#pragma unroll
      for (int m = 0; m < NKV; ++m) {
        const u16* kr = KVc + m * 1024 + dbase;     // 2 addrs/wave: broadcast
        f16x2 a0 = {(f16)0.f, (f16)0.f}, a1 = a0;
#pragma unroll
        for (int i = 0; i < 4; ++i) {
          f16x8 kv = *(const f16x8*)(kr + (i << 3));
          const f16x2* k2 = (const f16x2*)&kv;
          a0 += q2[i * 4 + 0] * k2[0];
          a1 += q2[i * 4 + 1] * k2[1];
          a0 += q2[i * 4 + 2] * k2[2];
          a1 += q2[i * 4 + 3] * k2[3];
        }
        f16x2 at = a0 + a1;
        float d = (float)at[0] + (float)at[1];
        d += __shfl_xor(d, 1);
        s[m] = d * 0.125f;
        mx = fmaxf(mx, s[m]);
      }
      float sum = 0.f;
#pragma unroll
      for (int m = 0; m < NKV; ++m) { s[m] = __expf(s[m] - mx); sum += s[m]; }
      f16x8 o8[4] = {};
#pragma unroll
      for (int m = 0; m < NKV; ++m) {
        f16 ah = (f16)s[m];
        f16x8 av = {ah, ah, ah, ah, ah, ah, ah, ah};
        const u16* vr = KVc + m * 1024 + 512 + dbase;
#pragma unroll
        for (int i = 0; i < 4; ++i) {
          f16x8 vv = *(const f16x8*)(vr + (i << 3));
          o8[i] += vv * av;                          // v_pk_fma_f16 x4
        }
      }
      size_t rowoff = (size_t)(b * 25 + n) * 512 + dbase;
      if (PMODE == 0 || PMODE == 1) {
        float sc = (1.f / sum) * (1.f / 3.f);
        float* orow = out + rowoff;
        const u16* xrow = xb + rowoff;
#pragma unroll
        for (int i = 0; i < 4; ++i) {
          f16x8 xv;
          if (PMODE == 0) xv = *(const f16x8*)(xrow + (i << 3));
#pragma unroll
          for (int j = 0; j < 8; j += 4) {
            float4 rr;
            if (PMODE == 0) {
              rr.x = (float)o8[i][j + 0] * sc + (float)xv[j + 0];
              rr.y = (float)o8[i][j + 1] * sc + (float)xv[j + 1];
              rr.z = (float)o8[i][j + 2] * sc + (float)xv[j + 2];
              rr.w = (float)o8[i][j + 3] * sc + (float)xv[j + 3];
            } else {
              float4 pv = *(const float4*)(orow + (i << 3) + j);
              rr.x = (float)o8[i][j + 0] * sc + pv.x;
              rr.y = (float)o8[i][j + 1] * sc + pv.y;
              rr.z = (float)o8[i][j + 2] * sc + pv.z;
              rr.w = (float)o8[i][j + 3] * sc + pv.w;
            }
            *(float4*)(orow + (i << 3) + j) = rr;
          }
        }
      } else if (PMODE == 2 || PMODE == 3) {
        float sc = 1.f / sum;
        u16* prow = p + rowoff;
#pragma unroll
        for (int i = 0; i < 4; ++i) {
          u16x8 pk;
          if (PMODE == 3) {
            f16x8 pv = *(const f16x8*)(prow + (i << 3));
#pragma unroll
            for (int j = 0; j < 8; ++j)
              pk[j] = f2h((float)o8[i][j] * sc + (float)pv[j]);
          } else {
#pragma unroll
            for (int j = 0; j < 8; ++j) pk[j] = f2h((float)o8[i][j] * sc);
          }
          *(u16x8*)(prow + (i << 3)) = pk;
        }
      } else {                                       // PMODE 4: final combine
        float sc = 1.f / sum;
        float* orow = out + rowoff;
        const u16* prow = p + rowoff;
        const u16* xrow = xb + rowoff;
#pragma unroll
        for (int i = 0; i < 4; ++i) {
          f16x8 pv = *(const f16x8*)(prow + (i << 3));
          f16x8 xv = *(const f16x8*)(xrow + (i << 3));
#pragma unroll
          for (int j = 0; j < 8; j += 4) {
            float4 rr;
            rr.x = (float)xv[j + 0] + ((float)pv[j + 0] + (float)o8[i][j + 0] * sc) * (1.f / 3.f);
            rr.y = (float)xv[j + 1] + ((float)pv[j + 1] + (float)o8[i][j + 1] * sc) * (1.f / 3.f);
            rr.z = (float)xv[j + 2] + ((float)pv[j + 2] + (float)o8[i][j + 2] * sc) * (1.f / 3.f);
            rr.w = (float)xv[j + 3] + ((float)pv[j + 3] + (float)o8[i][j + 3] * sc) * (1.f / 3.f);
            *(float4*)(orow + (i << 3) + j) = rr;
          }
        }
      }
    }
    asm volatile("s_waitcnt vmcnt(0)" ::: "memory");
    __syncthreads();
  }
}

// ---------------- pool: fc2 + softmax + S^T * l_feat ------------------------
template <int NIN, int NOUT>
__global__ __launch_bounds__(256) void pool(const u16* __restrict__ h,
    const u16* __restrict__ lf, const float* __restrict__ w2,
    const float* __restrict__ b2, u16* __restrict__ lout) {
  __shared__ __align__(16) float W2l[1024 * NOUT];
  __shared__ __align__(16) u16 Xl[NIN * 512];
  __shared__ __align__(16) float Sl[NIN * NOUT];
  int b = blockIdx.x, tid = threadIdx.x;
  for (int e = tid; e < 1024 * NOUT; e += 256) W2l[e] = w2[e];
  for (int e = tid * 8; e < NIN * 512; e += 2048)
    *(u16x8*)(Xl + e) = *(const u16x8*)(lf + (size_t)b * NIN * 512 + e);
  __syncthreads();
  if (tid < NIN * 8) {
    int nn = tid >> 3, sub = tid & 7;
    float pl[NOUT] = {};
    const u16* hr = h + (size_t)(b * NIN + nn) * 1024;
    for (int cc = 0; cc < 128; ++cc) {
      int c = sub + (cc << 3);
      float hv = h2f(hr[c]);
#pragma unroll
      for (int s2 = 0; s2 < NOUT; ++s2) pl[s2] += hv * W2l[c * NOUT + s2];
    }
#pragma unroll
    for (int s2 = 0; s2 < NOUT; ++s2) {
      pl[s2] += __shfl_down(pl[s2], 4, 8);
      pl[s2] += __shfl_down(pl[s2], 2, 8);
      pl[s2] += __shfl_down(pl[s2], 1, 8);
    }
    if (sub == 0) {
      float mx = -1e30f;
#pragma unroll
      for (int s2 = 0; s2 < NOUT; ++s2) { pl[s2] += b2[s2]; mx = fmaxf(mx, pl[s2]); }
      float sum = 0.f;
#pragma unroll
      for (int s2 = 0; s2 < NOUT; ++s2) { pl[s2] = __expf(pl[s2] - mx); sum += pl[s2]; }
      float inv = 1.f / sum;
#pragma unroll
      for (int s2 = 0; s2 < NOUT; ++s2) Sl[nn * NOUT + s2] = pl[s2] * inv;
    }
  }
  __syncthreads();
  int c0 = tid << 1;
#pragma unroll
  for (int s2 = 0; s2 < NOUT; ++s2) {
    float a0 = 0.f, a1 = 0.f;
#pragma unroll
    for (int nn = 0; nn < NIN; ++nn) {
      float wv = Sl[nn * NOUT + s2];
      a0 += wv * h2f(Xl[nn * 512 + c0]);
      a1 += wv * h2f(Xl[nn * 512 + c0 + 1]);
    }
    u32 pk = (u32)f2h(a0) | ((u32)f2h(a1) << 16);
    *(u32*)(lout + (size_t)(b * NOUT + s2) * 512 + c0) = pk;
  }
}

// ---------------- launcher ---------------------------------------------------
extern "C" void kernel_launch(void* const* d_in, const int* in_sizes, int n_in,
                              void* d_out, int out_size, void* d_ws, size_t ws_size,
                              hipStream_t stream) {
  const float* src = (const float*)d_in[0];
  const float* g    = (const float*)d_in[2];
  const float* bt   = (const float*)d_in[3];
  const float* Wq   = (const float*)d_in[4];
  const float* Wk   = (const float*)d_in[5];
  const float* Wv   = (const float*)d_in[6];
  const float* f0w  = (const float*)d_in[7];
  const float* f0b  = (const float*)d_in[8];
  const float* f0w2 = (const float*)d_in[9];
  const float* f0b2 = (const float*)d_in[10];
  const float* f1w  = (const float*)d_in[11];
  const float* f1b  = (const float*)d_in[12];
  const float* f1w2 = (const float*)d_in[13];
  const float* f1b2 = (const float*)d_in[14];
  float* out = (float*)d_out;
  char* ws = (char*)d_ws;

  // base layout (bytes), peak 503 MB (validated)
  u16* wt  = (u16*)(ws + 0);
  u16* xn  = (u16*)(ws + 6815744);
  u16* xb  = (u16*)(ws + 111673344);
  u16* qb  = (u16*)(ws + 216530944);
  u16* B1  = (u16*)(ws + 321388544);
  u16* l1  = (u16*)(ws + 426246144);
  u16* kn1 = (u16*)(ws + 476577792);
  u16* l2  = qb;
  u16* kn2 = qb + 14680064;
  // optional f16 partial-sum buffer (+105 MB, end 632 MB) — gated on ws_size
  bool bigws = ws_size >= 640000000ull;
  u16* pbuf = (u16*)(ws + 526909440);

  prep_w<<<13312, 256, 0, stream>>>(Wq, Wk, Wv, f0w, f1w, wt);
  ln_f32<<<25600, 256, 0, stream>>>(src, g, bt, xn, xb);

  // scale 0
  gemm_bt<false><<<dim3(4, 800), 256, 0, stream>>>(xn, wt, qb, nullptr, 102400, 512);
  for (int s = 0; s < 2; ++s) {
    size_t ro = (size_t)s * 51200;
    gemm_bt<false><<<dim3(8, 400), 256, 0, stream>>>(xn + ro * 512, wt + 786432, B1, nullptr, 51200, 1024);
    if (bigws)
      attn<25, 2, 1><<<256, 512, 0, stream>>>(qb + ro * 512, B1, xb + ro * 512, out + ro * 512, pbuf + ro * 512);
    else
      attn<25, 0, 1><<<256, 512, 0, stream>>>(qb + ro * 512, B1, xb + ro * 512, out + ro * 512, pbuf);
  }

  // pool 0
  for (int s = 0; s < 2; ++s) {
    size_t ro = (size_t)s * 51200;
    gemm_bt<true><<<dim3(8, 400), 256, 0, stream>>>(xb + ro * 512, wt + 2359296, B1, f0b, 51200, 1024);
    pool<25, 12><<<2048, 256, 0, stream>>>(B1, xb + ro * 512, f0w2, f0b2, l1 + (size_t)s * 2048 * 12 * 512);
  }
  ln_b16<<<12288, 256, 0, stream>>>(l1, g, bt, kn1);

  // scale 1
  gemm_bt<false><<<dim3(4, 800), 256, 0, stream>>>(xn, wt + 262144, qb, nullptr, 102400, 512);
  gemm_bt<false><<<dim3(8, 384), 256, 0, stream>>>(kn1, wt + 786432 + 524288, B1, nullptr, 49152, 1024);
  if (bigws)
    attn<12, 3, 2><<<512, 512, 0, stream>>>(qb, B1, xb, out, pbuf);
  else
    attn<12, 1, 2><<<512, 512, 0, stream>>>(qb, B1, xb, out, pbuf);

  // pool 1
  gemm_bt<true><<<dim3(8, 384), 256, 0, stream>>>(l1, wt + 2883584, B1, f1b, 49152, 1024);
  pool<12, 7><<<4096, 256, 0, stream>>>(B1, l1, f1w2, f1b2, l2);
  ln_b16<<<7168, 256, 0, stream>>>(l2, g, bt, kn2);

  // scale 2 (KV gemm before Q gemm: kn2 lives in qb region)
  gemm_bt<false><<<dim3(8, 224), 256, 0, stream>>>(kn2, wt + 786432 + 1048576, B1, nullptr, 28672, 1024);
  gemm_bt<false><<<dim3(4, 800), 256, 0, stream>>>(xn, wt + 524288, qb, nullptr, 102400, 512);
  if (bigws)
    attn<7, 4, 2><<<512, 512, 0, stream>>>(qb, B1, xb, out, pbuf);
  else
    attn<7, 1, 2><<<512, 512, 0, stream>>>(qb, B1, xb, out, pbuf);
}